// Round 5
// baseline (10471.777 us; speedup 1.0000x reference)
//
#include <hip/hip_runtime.h>
#include <hip/hip_bf16.h>
#include <hip/hip_cooperative_groups.h>
#include <math.h>

namespace cg = cooperative_groups;

#define HDIM 768
#define SDIM 512
#define VDIM 30522
#define BDIM 8
#define TLEN 32
#define H3   2304
#define VT   31034          // V + S
#define NEGV -1.0e6f
#define OFF2 ((size_t)BDIM * TLEN * VT)   // 7944704
#define NB   256
#define NT   512
#define NWAVE (NB * 8)      // 2048
#define VSL  954            // ceil(V/32)

// ---------------------------------------------------------------------------
// One wave computes dot(wrow, xv[b*:K]) for 8 batches. Result in lane 0.
// K4 = K/4 (compile-time constant at every call site -> fully unrolled).
// ---------------------------------------------------------------------------
__device__ __forceinline__ void mv_row8(const float* __restrict__ wrow,
                                        const float* __restrict__ xv,
                                        int K4, int lane, float acc[8])
{
#pragma unroll
    for (int b = 0; b < 8; b++) acc[b] = 0.f;
    for (int k4 = lane; k4 < K4; k4 += 64) {
        float4 w4 = ((const float4*)wrow)[k4];
#pragma unroll
        for (int b = 0; b < 8; b++) {
            float4 x4 = ((const float4*)(xv + b * (K4 * 4)))[k4];
            acc[b] += w4.x * x4.x + w4.y * x4.y + w4.z * x4.z + w4.w * x4.w;
        }
    }
#pragma unroll
    for (int b = 0; b < 8; b++) {
        float v = acc[b];
        for (int off = 32; off; off >>= 1) v += __shfl_down(v, off, 64);
        acc[b] = v;
    }
}

__global__ __launch_bounds__(NT) void decoder_persistent(
    const float* __restrict__ enc, const int* __restrict__ inputs,
    const int* __restrict__ cls, const float* __restrict__ emb,
    const float* __restrict__ attn_w, const float* __restrict__ attn_b,
    const float* __restrict__ copy_w, const float* __restrict__ copy_b,
    const float* __restrict__ w_ih, const float* __restrict__ w_hh,
    const float* __restrict__ b_ih, const float* __restrict__ b_hh,
    const float* __restrict__ out_w, const float* __restrict__ out_b,
    float* __restrict__ dout, float* __restrict__ ws)
{
    cg::grid_group grid = cg::this_grid();
    const int bid  = blockIdx.x;
    const int tid  = threadIdx.x;
    const int wid  = tid >> 6;
    const int lane = tid & 63;
    const int gw   = bid * 8 + wid;       // global wave id, 0..2047
    const int gidx = bid * NT + tid;      // 0..131071

    // ws carve-up (floats)
    float* hA  = ws;
    float* hB  = hA  + BDIM * HDIM;            // 6144
    float* x   = hB  + BDIM * HDIM;            // B*H3 = 18432
    float* thb = x   + BDIM * H3;              // 6144
    float* ghb = thb + BDIM * HDIM;            // 18432
    float* gi  = ghb + BDIM * H3;              // 18432
    float* th2 = gi  + BDIM * H3;              // 6144
    float* gen = th2 + BDIM * HDIM;            // 244176
    float* css = gen + (size_t)BDIM * VDIM;    // 4096
    float* atC = css + BDIM * SDIM;            // 8*32*768 = 196608
    float* atM = atC + BDIM * 32 * HDIM;       // 256
    float* atZ = atM + 256;                    // 256
    float* gM  = atZ + 256;                    // 256
    float* gZ  = gM  + 256;                    // 256
    float* argV = gZ + 256;                    // 256
    int*   argI = (int*)(argV + 256);          // 256

    __shared__ float sth[HDIM];
    __shared__ float swe[16];
    __shared__ float xs[BDIM * HDIM];          // 24 KB: staged h' for mv2
    __shared__ int   toks[SDIM];
    __shared__ float csss[SDIM];
    __shared__ float aggv[SDIM];
    __shared__ unsigned char ffl[SDIM];
    __shared__ float redf[NT];
    __shared__ int   redi[NT];
    __shared__ int   mlist[SDIM];
    __shared__ float mscore[SDIM];
    __shared__ int   wcnt[8], woff[8];
    __shared__ int   mtot;

    // ---------------- init ----------------
    {
        float clsv = (float)cls[0];
        for (int i = gidx; i < BDIM * VT; i += NB * NT) {
            int b = i / VT, v = i % VT;
            dout[(size_t)b * TLEN * VT + v] = (v == 0) ? clsv : 0.f;
        }
        if (gidx < BDIM) dout[OFF2 + (size_t)gidx * TLEN] = 1.0f;
        for (int i = gidx; i < BDIM * HDIM; i += NB * NT) {
            int b = i / HDIM, j = i % HDIM;
            hA[i] = 0.f;
            x[b * H3 + HDIM + j] = 0.f;               // sel = 0
            x[b * H3 + 2 * HDIM + j] = emb[HDIM + j]; // embedded(idx=1)
        }
    }
    grid.sync();

    // ---------------- PH1 (pre-loop): th,gh from hA ----------------
    for (int r = gw; r < HDIM + H3; r += NWAVE) {
        float acc[8];
        if (r < HDIM) {
            mv_row8(attn_w + (size_t)r * HDIM, hA, HDIM / 4, lane, acc);
            if (lane == 0) {
                float bb = attn_b[r];
#pragma unroll
                for (int b = 0; b < 8; b++) thb[b * HDIM + r] = acc[b] + bb;
            }
        } else {
            int rr = r - HDIM;
            mv_row8(w_hh + (size_t)rr * HDIM, hA, HDIM / 4, lane, acc);
            if (lane == 0) {
                float bb = b_hh[rr];
#pragma unroll
                for (int b = 0; b < 8; b++) ghb[b * H3 + rr] = acc[b] + bb;
            }
        }
    }
    grid.sync();

    for (int t = 0; t < TLEN - 1; t++) {
        const float* hin  = (t & 1) ? hB : hA;
        float*       hout = (t & 1) ? hA : hB;

        // ---------- PH2: attention partials (b,sub) = (bid>>5, bid&31) ----
        {
            int b = bid >> 5, sub = bid & 31, slo = sub * 16;
            for (int i = tid; i < HDIM; i += NT) sth[i] = thb[b * HDIM + i];
            __syncthreads();
            for (int j = 0; j < 2; j++) {
                int sl = wid * 2 + j;
                int s  = slo + sl;
                const float4* er = (const float4*)(enc + ((size_t)b * SDIM + s) * HDIM);
                const float4* tr = (const float4*)sth;
                float a = 0.f;
#pragma unroll
                for (int i = 0; i < 3; i++) {
                    float4 e = er[lane + i * 64], t4 = tr[lane + i * 64];
                    a += e.x * t4.x + e.y * t4.y + e.z * t4.z + e.w * t4.w;
                }
                for (int off = 32; off; off >>= 1) a += __shfl_down(a, off, 64);
                if (lane == 0) swe[sl] = a;
            }
            __syncthreads();
            if (tid == 0) {
                float m = swe[0];
                for (int i = 1; i < 16; i++) m = fmaxf(m, swe[i]);
                float z = 0.f;
                for (int i = 0; i < 16; i++) { float e = expf(swe[i] - m); swe[i] = e; z += e; }
                atM[b * 32 + sub] = m;
                atZ[b * 32 + sub] = z;
            }
            __syncthreads();
            for (int col = tid; col < HDIM; col += NT) {
                float acc = 0.f;
                const float* eb = enc + ((size_t)b * SDIM + slo) * HDIM + col;
#pragma unroll
                for (int s2 = 0; s2 < 16; s2++) acc += swe[s2] * eb[s2 * HDIM];
                atC[((size_t)b * 32 + sub) * HDIM + col] = acc;
            }
        }
        grid.sync();

        // ---------- PH2b: ctx combine -> x[:, 0:H) ----------
        if (gidx < BDIM * HDIM) {
            int b = gidx / HDIM, col = gidx % HDIM;
            float M = atM[b * 32];
#pragma unroll
            for (int i = 1; i < 32; i++) M = fmaxf(M, atM[b * 32 + i]);
            float Z = 0.f, acc = 0.f;
#pragma unroll
            for (int i = 0; i < 32; i++) {
                float sc = expf(atM[b * 32 + i] - M);
                Z += atZ[b * 32 + i] * sc;
                acc += atC[((size_t)b * 32 + i) * HDIM + col] * sc;
            }
            x[b * H3 + col] = acc / Z;
        }
        grid.sync();

        // ---------- PH3: gi = x @ w_ih.T + b_ih ----------
        for (int r = gw; r < H3; r += NWAVE) {
            float acc[8];
            mv_row8(w_ih + (size_t)r * H3, x, H3 / 4, lane, acc);
            if (lane == 0) {
                float bb = b_ih[r];
#pragma unroll
                for (int b = 0; b < 8; b++) gi[b * H3 + r] = acc[b] + bb;
            }
        }
        grid.sync();

        // ---------- PH5: gru (per-block into LDS) + th2/gen matvec ----------
        {
            for (int e = tid; e < BDIM * HDIM; e += NT) {
                int b = e / HDIM, j = e % HDIM;
                float gir = gi[b * H3 + j],            ghr = ghb[b * H3 + j];
                float giz = gi[b * H3 + HDIM + j],     ghz = ghb[b * H3 + HDIM + j];
                float gin = gi[b * H3 + 2 * HDIM + j], ghn = ghb[b * H3 + 2 * HDIM + j];
                float r = 1.f / (1.f + expf(-(gir + ghr)));
                float z = 1.f / (1.f + expf(-(giz + ghz)));
                float n = tanhf(gin + r * ghn);
                float hv = (1.f - z) * n + z * hin[e];
                xs[e] = hv;
                if (bid == 0) hout[e] = hv;
            }
            __syncthreads();
            for (int p = 0; p < 16; p++) {
                int r = gw + p * NWAVE;
                if (r >= HDIM + VDIM) break;
                float acc[8];
                if (r < HDIM) {
                    mv_row8(copy_w + (size_t)r * HDIM, xs, HDIM / 4, lane, acc);
                    if (lane == 0) {
                        float bb = copy_b[r];
#pragma unroll
                        for (int b = 0; b < 8; b++) th2[b * HDIM + r] = acc[b] + bb;
                    }
                } else {
                    int v = r - HDIM;
                    mv_row8(out_w + (size_t)v * HDIM, xs, HDIM / 4, lane, acc);
                    if (lane == 0) {
                        float bb = out_b[v];
#pragma unroll
                        for (int b = 0; b < 8; b++)
                            gen[(size_t)b * VDIM + v] = (v == 0) ? NEGV : acc[b] + bb;
                    }
                }
            }
        }
        grid.sync();

        // ---------- PH6: css (2 per wave) + gen stats (slice per block) ----
        {
            for (int j = 0; j < 2; j++) {
                int id = bid * 16 + wid * 2 + j;      // 0..4095
                int b = id >> 9, s = id & 511;
                const float4* er = (const float4*)(enc + ((size_t)b * SDIM + s) * HDIM);
                const float4* tr = (const float4*)(th2 + b * HDIM);
                float a = 0.f;
#pragma unroll
                for (int i = 0; i < 3; i++) {
                    float4 e = er[lane + i * 64], t4 = tr[lane + i * 64];
                    a += e.x * t4.x + e.y * t4.y + e.z * t4.z + e.w * t4.w;
                }
                for (int off = 32; off; off >>= 1) a += __shfl_down(a, off, 64);
                if (lane == 0) css[b * SDIM + s] = a;
            }
            __syncthreads();
            int b = bid >> 5, sub = bid & 31;
            int vlo = sub * VSL, vhi = min(VDIM, vlo + VSL);
            const float* grow = gen + (size_t)b * VDIM;
            float m = -INFINITY;
            for (int v = vlo + tid; v < vhi; v += NT) m = fmaxf(m, grow[v]);
            redf[tid] = m; __syncthreads();
            for (int off = 256; off; off >>= 1) {
                if (tid < off) redf[tid] = fmaxf(redf[tid], redf[tid + off]);
                __syncthreads();
            }
            float M = redf[0]; __syncthreads();
            float z = 0.f;
            for (int v = vlo + tid; v < vhi; v += NT) z += expf(grow[v] - M);
            redf[tid] = z; __syncthreads();
            for (int off = 256; off; off >>= 1) {
                if (tid < off) redf[tid] += redf[tid + off];
                __syncthreads();
            }
            if (tid == 0) { gM[b * 32 + sub] = M; gZ[b * 32 + sub] = redf[0]; }
        }
        grid.sync();

        // ---------- PH7: copy agg + combine + log-probs + argmax partial ---
        {
            int b = bid >> 5, sub = bid & 31;
            toks[tid] = inputs[b * SDIM + tid];
            csss[tid] = css[b * SDIM + tid];
            __syncthreads();
            {
                int tok = toks[tid]; int isf = 0; float agg = -INFINITY;
                if (tok != 0) {
                    isf = 1;
                    for (int s2 = 0; s2 < tid; s2++)
                        if (toks[s2] == tok) { isf = 0; break; }
                    if (isf) {
                        float ss = 0.f;
                        for (int s2 = tid; s2 < SDIM; s2++)
                            if (toks[s2] == tok) ss += csss[s2];
                        agg = ss;
                    }
                }
                ffl[tid] = (unsigned char)isf;
                aggv[tid] = agg;
            }
            __syncthreads();
            redf[tid] = ffl[tid] ? aggv[tid] : -INFINITY; __syncthreads();
            for (int off = 256; off; off >>= 1) {
                if (tid < off) redf[tid] = fmaxf(redf[tid], redf[tid + off]);
                __syncthreads();
            }
            float m9 = redf[0]; __syncthreads();
            redf[tid] = (ffl[tid] && m9 > -INFINITY) ? expf(aggv[tid] - m9) : 0.f;
            __syncthreads();
            for (int off = 256; off; off >>= 1) {
                if (tid < off) redf[tid] += redf[tid + off];
                __syncthreads();
            }
            float z9 = redf[0]; __syncthreads();

            float M = gM[b * 32];
#pragma unroll
            for (int i = 1; i < 32; i++) M = fmaxf(M, gM[b * 32 + i]);
            if (m9 > -INFINITY) M = fmaxf(M, m9);
            float Z = 0.f;
#pragma unroll
            for (int i = 0; i < 32; i++) Z += gZ[b * 32 + i] * expf(gM[b * 32 + i] - M);
            if (m9 > -INFINITY) Z += z9 * expf(m9 - M);
            float invZ = 1.f / Z;

            const float* grow = gen + (size_t)b * VDIM;
            float* orow = dout + ((size_t)b * TLEN + t + 1) * VT;
            int vlo = sub * VSL, vhi = min(VDIM, vlo + VSL);
            float best = -INFINITY; int bidx = 2147483647;
            for (int v = vlo + tid; v < vhi; v += NT) {
                float pg = expf(grow[v] - M) * invZ;
                float lp = logf(pg + 1e-10f);
                orow[v] = lp;
                if (lp > best) { best = lp; bidx = v; }
            }
            if (sub == 0) orow[VDIM + tid] = logf(1e-10f);
            __syncthreads();
            if (ffl[tid]) {
                int tok = toks[tid];
                if (tok >= vlo && tok < vhi) {
                    float pc = expf(aggv[tid] - M) * invZ;
                    float pg = expf(grow[tok] - M) * invZ;
                    float lp = logf(pg + pc + 1e-10f);
                    orow[tok] = lp;
                    if (lp > best || (lp == best && tok < bidx)) { best = lp; bidx = tok; }
                }
            }
            redf[tid] = best; redi[tid] = bidx; __syncthreads();
            for (int off = 256; off; off >>= 1) {
                if (tid < off) {
                    float v2 = redf[tid + off]; int i2 = redi[tid + off];
                    if (v2 > redf[tid] || (v2 == redf[tid] && i2 < redi[tid])) {
                        redf[tid] = v2; redi[tid] = i2;
                    }
                }
                __syncthreads();
            }
            if (tid == 0) { argV[b * 32 + sub] = redf[0]; argI[b * 32 + sub] = redi[0]; }
        }
        grid.sync();

        // ---------- PH8: blocks 0..7 tail_d  |  blocks 8..255 next th/gh ---
        {
            if (bid < BDIM) {
                int b = bid;
                float best = argV[b * 32]; int samp = argI[b * 32];
#pragma unroll
                for (int i = 1; i < 32; i++) {
                    float v = argV[b * 32 + i];
                    if (v > best) { best = v; samp = argI[b * 32 + i]; }
                }
                if (tid == 0) dout[OFF2 + (size_t)b * TLEN + t + 1] = (float)samp;
                toks[tid] = inputs[b * SDIM + tid];
                csss[tid] = css[b * SDIM + tid];
                __syncthreads();
                int flag = (toks[tid] == samp);
                redf[tid] = flag ? fabsf(csss[tid]) : 0.f;
                __syncthreads();
                for (int off = 256; off; off >>= 1) {
                    if (tid < off) redf[tid] += redf[tid + off];
                    __syncthreads();
                }
                float den = fmaxf(redf[0], 1e-12f);
                __syncthreads();
                unsigned long long mk = __ballot(flag);
                if (lane == 0) wcnt[wid] = __popcll(mk);
                __syncthreads();
                if (tid == 0) {
                    int o = 0;
                    for (int w = 0; w < 8; w++) { woff[w] = o; o += wcnt[w]; }
                    mtot = o;
                }
                __syncthreads();
                if (flag) {
                    int pos = woff[wid] + __popcll(mk & ((1ULL << lane) - 1ULL));
                    mlist[pos] = tid;
                    mscore[pos] = csss[tid] / den;
                }
                __syncthreads();
                int mc = mtot;
                int ic = (samp > VDIM) ? 3 : samp;
                if (ic >= VDIM) ic = VDIM - 1;
                for (int col = tid; col < HDIM; col += NT) {
                    float sel = 0.f;
                    for (int mI = 0; mI < mc; mI++)
                        sel += mscore[mI] * enc[((size_t)b * SDIM + mlist[mI]) * HDIM + col];
                    x[b * H3 + HDIM + col] = sel;
                    x[b * H3 + 2 * HDIM + col] = emb[(size_t)ic * HDIM + col];
                }
            } else {
                const float* hnext = hout;
                int w2 = (bid - BDIM) * 8 + wid;          // 0..1983
                for (int r = w2; r < HDIM + H3; r += (NB - BDIM) * 8) {
                    float acc[8];
                    if (r < HDIM) {
                        mv_row8(attn_w + (size_t)r * HDIM, hnext, HDIM / 4, lane, acc);
                        if (lane == 0) {
                            float bb = attn_b[r];
#pragma unroll
                            for (int b = 0; b < 8; b++) thb[b * HDIM + r] = acc[b] + bb;
                        }
                    } else {
                        int rr = r - HDIM;
                        mv_row8(w_hh + (size_t)rr * HDIM, hnext, HDIM / 4, lane, acc);
                        if (lane == 0) {
                            float bb = b_hh[rr];
#pragma unroll
                            for (int b = 0; b < 8; b++) ghb[b * H3 + rr] = acc[b] + bb;
                        }
                    }
                }
            }
        }
        grid.sync();
    }
}

// ---------------------------------------------------------------------------
extern "C" void kernel_launch(void* const* d_in, const int* in_sizes, int n_in,
                              void* d_out, int out_size, void* d_ws, size_t ws_size,
                              hipStream_t stream)
{
    const float* enc    = (const float*)d_in[0];
    const int*   inputs = (const int*)d_in[1];
    const int*   cls    = (const int*)d_in[2];
    const float* emb    = (const float*)d_in[4];
    const float* attn_w = (const float*)d_in[5];
    const float* attn_b = (const float*)d_in[6];
    const float* copy_w = (const float*)d_in[7];
    const float* copy_b = (const float*)d_in[8];
    const float* w_ih   = (const float*)d_in[9];
    const float* w_hh   = (const float*)d_in[10];
    const float* b_ih   = (const float*)d_in[11];
    const float* b_hh   = (const float*)d_in[12];
    const float* out_w  = (const float*)d_in[13];
    const float* out_b  = (const float*)d_in[14];
    float* dout = (float*)d_out;
    float* ws   = (float*)d_ws;

    void* kargs[] = {
        (void*)&enc, (void*)&inputs, (void*)&cls, (void*)&emb,
        (void*)&attn_w, (void*)&attn_b, (void*)&copy_w, (void*)&copy_b,
        (void*)&w_ih, (void*)&w_hh, (void*)&b_ih, (void*)&b_hh,
        (void*)&out_w, (void*)&out_b, (void*)&dout, (void*)&ws
    };
    hipLaunchCooperativeKernel((const void*)decoder_persistent,
                               dim3(NB), dim3(NT), kargs, 0, stream);
}

// Round 6
// 3766.477 us; speedup vs baseline: 2.7803x; 2.7803x over previous
//
#include <hip/hip_runtime.h>
#include <hip/hip_bf16.h>
#include <math.h>

#define HDIM 768
#define SDIM 512
#define VDIM 30522
#define BDIM 8
#define TLEN 32
#define H3   2304
#define VT   31034          // V + S
#define NEGV -1.0e6f
#define OFF2 ((size_t)BDIM * TLEN * VT)   // 7944704
#define SSLICE 64                          // s-slice per combo block
#define VSLICE 3816                        // ceil(V/8)
#define NROWS (HDIM + VDIM + HDIM + H3)    // 34362 bigmv rows

// ---------------------------------------------------------------------------
// One wave: dot(wrow, xv[b*K : b*K+K]) for 8 batches; result in lane 0.
// ---------------------------------------------------------------------------
__device__ __forceinline__ void mv_row8(const float* __restrict__ wrow,
                                        const float* __restrict__ xv,
                                        int K4, int lane, float acc[8])
{
#pragma unroll
    for (int b = 0; b < 8; b++) acc[b] = 0.f;
    for (int k4 = lane; k4 < K4; k4 += 64) {
        float4 w4 = ((const float4*)wrow)[k4];
#pragma unroll
        for (int b = 0; b < 8; b++) {
            float4 x4 = ((const float4*)(xv + b * (K4 * 4)))[k4];
            acc[b] += w4.x * x4.x + w4.y * x4.y + w4.z * x4.z + w4.w * x4.w;
        }
    }
#pragma unroll
    for (int b = 0; b < 8; b++) {
        float v = acc[b];
        for (int off = 32; off; off >>= 1) v += __shfl_down(v, off, 64);
        acc[b] = v;
    }
}

// ---------------------------------------------------------------------------
// Boot: dout init; h0 = 0; th0 = attn_b; gh0 = b_hh; x sel/emb init.
// ---------------------------------------------------------------------------
__global__ __launch_bounds__(256) void boot_kernel(
    float* __restrict__ dout, const int* __restrict__ cls,
    float* __restrict__ hA, float* __restrict__ x,
    const float* __restrict__ emb, float* __restrict__ thb,
    float* __restrict__ ghb, const float* __restrict__ attn_b,
    const float* __restrict__ b_hh)
{
    int gidx = blockIdx.x * 256 + threadIdx.x;
    int stride = gridDim.x * 256;
    float clsv = (float)cls[0];
    for (int i = gidx; i < BDIM * VT; i += stride) {
        int b = i / VT, v = i % VT;
        dout[(size_t)b * TLEN * VT + v] = (v == 0) ? clsv : 0.f;
    }
    if (gidx < BDIM) dout[OFF2 + (size_t)gidx * TLEN] = 1.0f;
    for (int i = gidx; i < BDIM * HDIM; i += stride) {
        int b = i / HDIM, j = i % HDIM;
        hA[i] = 0.f;
        x[b * H3 + HDIM + j] = 0.f;
        x[b * H3 + 2 * HDIM + j] = emb[HDIM + j];
        thb[i] = attn_b[j];
    }
    for (int i = gidx; i < BDIM * H3; i += stride)
        ghb[i] = b_hh[i % H3];
}

// ---------------------------------------------------------------------------
// grufull: gi rows (3 per output) + GRU combine, fused. 96 blocks x 512.
// wave j = bid*8+wid in [0,768). h' -> hout.
// ---------------------------------------------------------------------------
__global__ __launch_bounds__(512) void grufull_kernel(
    const float* __restrict__ w_ih, const float* __restrict__ b_ih,
    const float* __restrict__ x, const float* __restrict__ ghb,
    const float* __restrict__ hin, float* __restrict__ hout)
{
    int wid = threadIdx.x >> 6, lane = threadIdx.x & 63;
    int j = blockIdx.x * 8 + wid;
    if (j >= HDIM) return;

    float a0[8], a1[8], a2[8];
    mv_row8(w_ih + (size_t)(0 * HDIM + j) * H3, x, H3 / 4, lane, a0);
    mv_row8(w_ih + (size_t)(1 * HDIM + j) * H3, x, H3 / 4, lane, a1);
    mv_row8(w_ih + (size_t)(2 * HDIM + j) * H3, x, H3 / 4, lane, a2);
    if (lane == 0) {
        float bi_r = b_ih[j], bi_z = b_ih[HDIM + j], bi_n = b_ih[2 * HDIM + j];
#pragma unroll
        for (int b = 0; b < 8; b++) {
            float gir = a0[b] + bi_r;
            float giz = a1[b] + bi_z;
            float gin = a2[b] + bi_n;
            float ghr = ghb[b * H3 + j];
            float ghz = ghb[b * H3 + HDIM + j];
            float ghn = ghb[b * H3 + 2 * HDIM + j];
            float r = 1.f / (1.f + expf(-(gir + ghr)));
            float z = 1.f / (1.f + expf(-(giz + ghz)));
            float n = tanhf(gin + r * ghn);
            hout[b * HDIM + j] = (1.f - z) * n + z * hin[b * HDIM + j];
        }
    }
}

// ---------------------------------------------------------------------------
// bigmv: stream copy_w | out_w | attn_w | w_hh against LDS-staged h'.
// 4296 blocks x 512 (8 waves, one row each).
// ---------------------------------------------------------------------------
__global__ __launch_bounds__(512) void bigmv_kernel(
    const float* __restrict__ copy_w, const float* __restrict__ copy_b,
    const float* __restrict__ out_w,  const float* __restrict__ out_b,
    const float* __restrict__ attn_w, const float* __restrict__ attn_b,
    const float* __restrict__ w_hh,   const float* __restrict__ b_hh,
    const float* __restrict__ hp, float* __restrict__ th2,
    float* __restrict__ gen, float* __restrict__ thb,
    float* __restrict__ ghb)
{
    __shared__ float xs[BDIM * HDIM];
    for (int i = threadIdx.x; i < BDIM * HDIM; i += 512)
        xs[i] = hp[i];
    __syncthreads();

    int wid = threadIdx.x >> 6, lane = threadIdx.x & 63;
    int r = blockIdx.x * 8 + wid;
    if (r >= NROWS) return;

    float acc[8];
    if (r < HDIM) {                                   // copy_w -> th2
        mv_row8(copy_w + (size_t)r * HDIM, xs, HDIM / 4, lane, acc);
        if (lane == 0) {
            float bb = copy_b[r];
#pragma unroll
            for (int b = 0; b < 8; b++) th2[b * HDIM + r] = acc[b] + bb;
        }
    } else if (r < HDIM + VDIM) {                     // out_w -> gen
        int v = r - HDIM;
        mv_row8(out_w + (size_t)v * HDIM, xs, HDIM / 4, lane, acc);
        if (lane == 0) {
            float bb = out_b[v];
#pragma unroll
            for (int b = 0; b < 8; b++)
                gen[(size_t)b * VDIM + v] = (v == 0) ? NEGV : acc[b] + bb;
        }
    } else if (r < HDIM + VDIM + HDIM) {              // attn_w -> th (next)
        int rr = r - HDIM - VDIM;
        mv_row8(attn_w + (size_t)rr * HDIM, xs, HDIM / 4, lane, acc);
        if (lane == 0) {
            float bb = attn_b[rr];
#pragma unroll
            for (int b = 0; b < 8; b++) thb[b * HDIM + rr] = acc[b] + bb;
        }
    } else {                                          // w_hh -> gh (next)
        int rr = r - HDIM - VDIM - HDIM;
        mv_row8(w_hh + (size_t)rr * HDIM, xs, HDIM / 4, lane, acc);
        if (lane == 0) {
            float bb = b_hh[rr];
#pragma unroll
            for (int b = 0; b < 8; b++) ghb[b * H3 + rr] = acc[b] + bb;
        }
    }
}

// ---------------------------------------------------------------------------
// combo: block (b,sub): enc s-slice -> scores(t+1) (vs th) AND css(t) (vs
// th2) in one pass; attn softmax partial + partial context; gen-stats slice.
// 64 blocks x 512.
// ---------------------------------------------------------------------------
__global__ __launch_bounds__(512) void combo_kernel(
    const float* __restrict__ enc, const float* __restrict__ thb,
    const float* __restrict__ th2, float* __restrict__ css,
    float* __restrict__ atC, float* __restrict__ atM, float* __restrict__ atZ,
    const float* __restrict__ gen, float* __restrict__ gM,
    float* __restrict__ gZ, int do_cg)
{
    __shared__ float sth[HDIM];
    __shared__ float sth2[HDIM];
    __shared__ float swe[SSLICE];
    __shared__ float red[8];
    int blk = blockIdx.x, b = blk >> 3, sub = blk & 7;
    int tid = threadIdx.x, wid = tid >> 6, lane = tid & 63;
    int slo = sub * SSLICE;

    for (int i = tid; i < HDIM; i += 512) {
        sth[i]  = thb[b * HDIM + i];
        sth2[i] = th2[b * HDIM + i];
    }
    __syncthreads();

    // dual dots per enc row
    for (int j = 0; j < 8; j++) {
        int sl = wid * 8 + j, s = slo + sl;
        const float4* er = (const float4*)(enc + ((size_t)b * SDIM + s) * HDIM);
        float a1 = 0.f, a2 = 0.f;
#pragma unroll
        for (int i = 0; i < 3; i++) {
            float4 e = er[lane + i * 64];
            float4 t1 = ((const float4*)sth)[lane + i * 64];
            float4 t2 = ((const float4*)sth2)[lane + i * 64];
            a1 += e.x * t1.x + e.y * t1.y + e.z * t1.z + e.w * t1.w;
            a2 += e.x * t2.x + e.y * t2.y + e.z * t2.z + e.w * t2.w;
        }
        for (int off = 32; off; off >>= 1) {
            a1 += __shfl_down(a1, off, 64);
            a2 += __shfl_down(a2, off, 64);
        }
        if (lane == 0) {
            swe[sl] = a1;
            if (do_cg) css[b * SDIM + s] = a2;
        }
    }
    __syncthreads();

    // softmax partial over the 64 scores
    if (tid < 64) {
        float v = swe[tid];
        float m = v;
        for (int off = 32; off; off >>= 1) m = fmaxf(m, __shfl_xor(m, off, 64));
        float e = expf(v - m);
        float z = e;
        for (int off = 32; off; off >>= 1) z += __shfl_xor(z, off, 64);
        swe[tid] = e;
        if (tid == 0) { atM[b * 8 + sub] = m; atZ[b * 8 + sub] = z; }
    }
    __syncthreads();

    // partial context (coalesced cols)
    for (int col = tid; col < HDIM; col += 512) {
        float acc = 0.f;
        const float* eb = enc + ((size_t)b * SDIM + slo) * HDIM + col;
#pragma unroll 8
        for (int s2 = 0; s2 < SSLICE; s2++) acc += swe[s2] * eb[s2 * HDIM];
        atC[((size_t)b * 8 + sub) * HDIM + col] = acc;
    }

    if (!do_cg) return;

    // gen stats over v-slice
    int vlo = sub * VSLICE, vhi = min(VDIM, vlo + VSLICE);
    const float* grow = gen + (size_t)b * VDIM;
    float m = -INFINITY;
    for (int v = vlo + tid; v < vhi; v += 512) m = fmaxf(m, grow[v]);
    for (int off = 32; off; off >>= 1) m = fmaxf(m, __shfl_xor(m, off, 64));
    if (lane == 0) red[wid] = m;
    __syncthreads();
    float M = red[0];
#pragma unroll
    for (int w = 1; w < 8; w++) M = fmaxf(M, red[w]);
    float z = 0.f;
    for (int v = vlo + tid; v < vhi; v += 512) z += expf(grow[v] - M);
    for (int off = 32; off; off >>= 1) z += __shfl_xor(z, off, 64);
    __syncthreads();
    if (lane == 0) red[wid] = z;
    __syncthreads();
    if (tid == 0) {
        float Z = 0.f;
#pragma unroll
        for (int w = 0; w < 8; w++) Z += red[w];
        gM[b * 8 + sub] = M;
        gZ[b * 8 + sub] = Z;
    }
}

// ---------------------------------------------------------------------------
// tailc: copy agg + M/Z combine + log-probs + argmax partials. 64 x 1024.
// ---------------------------------------------------------------------------
__global__ __launch_bounds__(1024) void tailc_kernel(
    const float* __restrict__ gen, const float* __restrict__ css,
    const int* __restrict__ inputs, const float* __restrict__ genM,
    const float* __restrict__ genZ, float* __restrict__ dout,
    float* __restrict__ argV, int* __restrict__ argI, int t)
{
    __shared__ int   toks[SDIM];
    __shared__ float csss[SDIM];
    __shared__ float aggv[SDIM];
    __shared__ unsigned char ffl[SDIM];
    __shared__ float redf[1024];
    __shared__ int   redi[1024];
    int blk = blockIdx.x, b = blk >> 3, sub = blk & 7;
    int tid = threadIdx.x;

    if (tid < SDIM) {
        toks[tid] = inputs[b * SDIM + tid];
        csss[tid] = css[b * SDIM + tid];
    }
    __syncthreads();

    if (tid < SDIM) {
        int tok = toks[tid]; int isf = 0; float agg = -INFINITY;
        if (tok != 0) {
            isf = 1;
            for (int s2 = 0; s2 < tid; s2++)
                if (toks[s2] == tok) { isf = 0; break; }
            if (isf) {
                float ss = 0.f;
                for (int s2 = tid; s2 < SDIM; s2++)
                    if (toks[s2] == tok) ss += csss[s2];
                agg = ss;
            }
        }
        ffl[tid] = (unsigned char)isf;
        aggv[tid] = agg;
    }
    __syncthreads();

    redf[tid] = (tid < SDIM && ffl[tid]) ? aggv[tid] : -INFINITY;
    __syncthreads();
    for (int off = 512; off; off >>= 1) {
        if (tid < off) redf[tid] = fmaxf(redf[tid], redf[tid + off]);
        __syncthreads();
    }
    float m9 = redf[0]; __syncthreads();
    redf[tid] = (tid < SDIM && ffl[tid] && m9 > -INFINITY)
                    ? expf(aggv[tid] - m9) : 0.f;
    __syncthreads();
    for (int off = 512; off; off >>= 1) {
        if (tid < off) redf[tid] += redf[tid + off];
        __syncthreads();
    }
    float z9 = redf[0]; __syncthreads();

    float M = genM[b * 8 + 0];
#pragma unroll
    for (int i = 1; i < 8; i++) M = fmaxf(M, genM[b * 8 + i]);
    if (m9 > -INFINITY) M = fmaxf(M, m9);
    float Z = 0.f;
#pragma unroll
    for (int i = 0; i < 8; i++) Z += genZ[b * 8 + i] * expf(genM[b * 8 + i] - M);
    if (m9 > -INFINITY) Z += z9 * expf(m9 - M);
    float invZ = 1.f / Z;

    const float* grow = gen + (size_t)b * VDIM;
    float* orow = dout + ((size_t)b * TLEN + t + 1) * VT;
    int vlo = sub * VSLICE, vhi = min(VDIM, vlo + VSLICE);
    float best = -INFINITY; int bidx = 2147483647;
    for (int v = vlo + tid; v < vhi; v += 1024) {
        float pg = expf(grow[v] - M) * invZ;
        float lp = logf(pg + 1e-10f);
        orow[v] = lp;
        if (lp > best) { best = lp; bidx = v; }
    }
    if (sub == 0 && tid < SDIM) orow[VDIM + tid] = logf(1e-10f);
    __syncthreads();

    if (tid < SDIM && ffl[tid]) {
        int tok = toks[tid];
        if (tok >= vlo && tok < vhi) {
            float pc = expf(aggv[tid] - M) * invZ;
            float pg = expf(grow[tok] - M) * invZ;
            float lp = logf(pg + pc + 1e-10f);
            orow[tok] = lp;
            if (lp > best || (lp == best && tok < bidx)) { best = lp; bidx = tok; }
        }
    }
    redf[tid] = best; redi[tid] = bidx; __syncthreads();
    for (int off = 512; off; off >>= 1) {
        if (tid < off) {
            float v2 = redf[tid + off]; int i2 = redi[tid + off];
            if (v2 > redf[tid] || (v2 == redf[tid] && i2 < redi[tid])) {
                redf[tid] = v2; redi[tid] = i2;
            }
        }
        __syncthreads();
    }
    if (tid == 0) { argV[b * 8 + sub] = redf[0]; argI[b * 8 + sub] = redi[0]; }
}

// ---------------------------------------------------------------------------
// mix: blocks 0..7 = tail_d (argmax combine, samp, selread+embed);
//      blocks 8..15 = attn_fin (ctx combine -> x[:,0:H)). 16 x 1024.
// ---------------------------------------------------------------------------
__global__ __launch_bounds__(1024) void mix_kernel(
    const float* __restrict__ enc, const float* __restrict__ css,
    const int* __restrict__ inputs, const float* __restrict__ argV,
    const int* __restrict__ argI, const float* __restrict__ emb,
    float* __restrict__ dout, float* __restrict__ x,
    const float* __restrict__ atC, const float* __restrict__ atM,
    const float* __restrict__ atZ, int t, int do_tail)
{
    __shared__ int   toks[SDIM];
    __shared__ float csss[SDIM];
    __shared__ float redf[1024];
    __shared__ int   mlist[SDIM];
    __shared__ float mscore[SDIM];
    __shared__ int   wcnt[16], woff[16];
    __shared__ int   mtot;
    int bid = blockIdx.x, tid = threadIdx.x;

    if (bid >= BDIM) {
        // attn_fin
        int b = bid - BDIM;
        if (tid < HDIM) {
            float m[8], z[8];
#pragma unroll
            for (int i = 0; i < 8; i++) { m[i] = atM[b * 8 + i]; z[i] = atZ[b * 8 + i]; }
            float M = m[0];
#pragma unroll
            for (int i = 1; i < 8; i++) M = fmaxf(M, m[i]);
            float Z = 0.f;
#pragma unroll
            for (int i = 0; i < 8; i++) Z += z[i] * expf(m[i] - M);
            float acc = 0.f;
#pragma unroll
            for (int i = 0; i < 8; i++)
                acc += atC[((size_t)b * 8 + i) * HDIM + tid] * expf(m[i] - M);
            x[b * H3 + tid] = acc / Z;
        }
        return;
    }
    if (!do_tail) return;

    int b = bid;
    float best = argV[b * 8 + 0]; int samp = argI[b * 8 + 0];
#pragma unroll
    for (int i = 1; i < 8; i++) {
        float v = argV[b * 8 + i];
        if (v > best) { best = v; samp = argI[b * 8 + i]; }
    }
    if (tid == 0) dout[OFF2 + (size_t)b * TLEN + t + 1] = (float)samp;

    if (tid < SDIM) {
        toks[tid] = inputs[b * SDIM + tid];
        csss[tid] = css[b * SDIM + tid];
    }
    __syncthreads();

    int flag = (tid < SDIM) ? (toks[tid] == samp) : 0;
    redf[tid] = flag ? fabsf(csss[tid]) : 0.f;
    __syncthreads();
    for (int off = 512; off; off >>= 1) {
        if (tid < off) redf[tid] += redf[tid + off];
        __syncthreads();
    }
    float den = fmaxf(redf[0], 1e-12f);
    __syncthreads();

    unsigned long long mk = __ballot(flag);
    int wv = tid >> 6, ln = tid & 63;
    if (ln == 0) wcnt[wv] = __popcll(mk);
    __syncthreads();
    if (tid == 0) {
        int o = 0;
        for (int w = 0; w < 16; w++) { woff[w] = o; o += wcnt[w]; }
        mtot = o;
    }
    __syncthreads();
    if (flag) {
        int pos = woff[wv] + __popcll(mk & ((1ULL << ln) - 1ULL));
        mlist[pos] = tid;
        mscore[pos] = csss[tid] / den;
    }
    __syncthreads();
    int mc = mtot;

    if (tid < HDIM) {
        float sel = 0.f;
        for (int mI = 0; mI < mc; mI++)
            sel += mscore[mI] * enc[((size_t)b * SDIM + mlist[mI]) * HDIM + tid];
        x[b * H3 + HDIM + tid] = sel;
        int ic = (samp > VDIM) ? 3 : samp;
        if (ic >= VDIM) ic = VDIM - 1;
        x[b * H3 + 2 * HDIM + tid] = emb[(size_t)ic * HDIM + tid];
    }
}

// ---------------------------------------------------------------------------
extern "C" void kernel_launch(void* const* d_in, const int* in_sizes, int n_in,
                              void* d_out, int out_size, void* d_ws, size_t ws_size,
                              hipStream_t stream)
{
    const float* enc    = (const float*)d_in[0];
    const int*   inputs = (const int*)d_in[1];
    const int*   cls    = (const int*)d_in[2];
    const float* emb    = (const float*)d_in[4];
    const float* attn_w = (const float*)d_in[5];
    const float* attn_b = (const float*)d_in[6];
    const float* copy_w = (const float*)d_in[7];
    const float* copy_b = (const float*)d_in[8];
    const float* w_ih   = (const float*)d_in[9];
    const float* w_hh   = (const float*)d_in[10];
    const float* b_ih   = (const float*)d_in[11];
    const float* b_hh   = (const float*)d_in[12];
    const float* out_w  = (const float*)d_in[13];
    const float* out_b  = (const float*)d_in[14];
    float* dout = (float*)d_out;

    float* ws   = (float*)d_ws;
    float* hA   = ws;                          // B*H
    float* hB   = hA  + BDIM * HDIM;           // B*H
    float* x    = hB  + BDIM * HDIM;           // B*H3
    float* thb  = x   + BDIM * H3;             // B*H
    float* ghb  = thb + BDIM * HDIM;           // B*H3
    float* th2  = ghb + BDIM * H3;             // B*H
    float* gen  = th2 + BDIM * HDIM;           // B*V
    float* css  = gen + (size_t)BDIM * VDIM;   // B*S
    float* atC  = css + BDIM * SDIM;           // B*8*H
    float* atM  = atC + BDIM * 8 * HDIM;       // 64
    float* atZ  = atM + 64;
    float* gM   = atZ + 64;
    float* gZ   = gM  + 64;
    float* argV = gZ  + 64;
    int*   argI = (int*)(argV + 64);

    boot_kernel<<<512, 256, 0, stream>>>(dout, cls, hA, x, emb, thb, ghb,
                                         attn_b, b_hh);
    // attention partials for t=0 (scores from th0; no css/gen yet)
    combo_kernel<<<64, 512, 0, stream>>>(enc, thb, th2, css, atC, atM, atZ,
                                         gen, gM, gZ, 0);
    // ctx combine -> x0 (tail off)
    mix_kernel<<<16, 1024, 0, stream>>>(enc, css, inputs, argV, argI, emb,
                                        dout, x, atC, atM, atZ, 0, 0);

    for (int t = 0; t < TLEN - 1; t++) {
        const float* hin  = (t & 1) ? hB : hA;
        float*       hout = (t & 1) ? hA : hB;
        grufull_kernel<<<96, 512, 0, stream>>>(w_ih, b_ih, x, ghb, hin, hout);
        bigmv_kernel<<<(NROWS + 7) / 8, 512, 0, stream>>>(
            copy_w, copy_b, out_w, out_b, attn_w, attn_b, w_hh, b_hh,
            hout, th2, gen, thb, ghb);
        combo_kernel<<<64, 512, 0, stream>>>(enc, thb, th2, css, atC, atM, atZ,
                                             gen, gM, gZ, 1);
        tailc_kernel<<<64, 1024, 0, stream>>>(gen, css, inputs, gM, gZ,
                                              dout, argV, argI, t);
        mix_kernel<<<16, 1024, 0, stream>>>(enc, css, inputs, argV, argI, emb,
                                            dout, x, atC, atM, atZ, t, 1);
    }
}

// Round 7
// 3761.013 us; speedup vs baseline: 2.7843x; 1.0015x over previous
//
#include <hip/hip_runtime.h>
#include <hip/hip_bf16.h>
#include <math.h>

#define HDIM 768
#define SDIM 512
#define VDIM 30522
#define BDIM 8
#define TLEN 32
#define H3   2304
#define VT   31034          // V + S
#define NEGV -1.0e6f
#define OFF2 ((size_t)BDIM * TLEN * VT)   // 7944704
#define SSLICE 64                          // s-slice per combo block
#define VSLICE 3816                        // ceil(V/8)
#define NROWS (HDIM + VDIM + HDIM + H3)    // 34362 bigmv rows

// ---------------------------------------------------------------------------
// One wave: dot(wrow, xv[b*K : b*K+K]) for 8 batches; result in lane 0.
// ---------------------------------------------------------------------------
__device__ __forceinline__ void mv_row8(const float* __restrict__ wrow,
                                        const float* __restrict__ xv,
                                        int K4, int lane, float acc[8])
{
#pragma unroll
    for (int b = 0; b < 8; b++) acc[b] = 0.f;
    for (int k4 = lane; k4 < K4; k4 += 64) {
        float4 w4 = ((const float4*)wrow)[k4];
#pragma unroll
        for (int b = 0; b < 8; b++) {
            float4 x4 = ((const float4*)(xv + b * (K4 * 4)))[k4];
            acc[b] += w4.x * x4.x + w4.y * x4.y + w4.z * x4.z + w4.w * x4.w;
        }
    }
#pragma unroll
    for (int b = 0; b < 8; b++) {
        float v = acc[b];
        for (int off = 32; off; off >>= 1) v += __shfl_down(v, off, 64);
        acc[b] = v;
    }
}

// ---------------------------------------------------------------------------
// Boot: dout init; h0 = 0; th0 = attn_b; gh0 = b_hh; x sel/emb init.
// ---------------------------------------------------------------------------
__global__ __launch_bounds__(256) void boot_kernel(
    float* __restrict__ dout, const int* __restrict__ cls,
    float* __restrict__ hA, float* __restrict__ x,
    const float* __restrict__ emb, float* __restrict__ thb,
    float* __restrict__ ghb, const float* __restrict__ attn_b,
    const float* __restrict__ b_hh)
{
    int gidx = blockIdx.x * 256 + threadIdx.x;
    int stride = gridDim.x * 256;
    float clsv = (float)cls[0];
    for (int i = gidx; i < BDIM * VT; i += stride) {
        int b = i / VT, v = i % VT;
        dout[(size_t)b * TLEN * VT + v] = (v == 0) ? clsv : 0.f;
    }
    if (gidx < BDIM) dout[OFF2 + (size_t)gidx * TLEN] = 1.0f;
    for (int i = gidx; i < BDIM * HDIM; i += stride) {
        int b = i / HDIM, j = i % HDIM;
        hA[i] = 0.f;
        x[b * H3 + HDIM + j] = 0.f;
        x[b * H3 + 2 * HDIM + j] = emb[HDIM + j];
        thb[i] = attn_b[j];
    }
    for (int i = gidx; i < BDIM * H3; i += stride)
        ghb[i] = b_hh[i % H3];
}

// ---------------------------------------------------------------------------
// grufull: all 3 gate rows of gi for output j computed in ONE k-loop
// (x4 loaded once, used by 3 gates), then GRU combine. 96 blocks x 512.
// ---------------------------------------------------------------------------
__global__ __launch_bounds__(512) void grufull_kernel(
    const float* __restrict__ w_ih, const float* __restrict__ b_ih,
    const float* __restrict__ x, const float* __restrict__ ghb,
    const float* __restrict__ hin, float* __restrict__ hout)
{
    int wid = threadIdx.x >> 6, lane = threadIdx.x & 63;
    int j = blockIdx.x * 8 + wid;
    if (j >= HDIM) return;

    const float4* wr = (const float4*)(w_ih + (size_t)j * H3);
    const float4* wz = (const float4*)(w_ih + (size_t)(HDIM + j) * H3);
    const float4* wn = (const float4*)(w_ih + (size_t)(2 * HDIM + j) * H3);

    float ar[8], az[8], an[8];
#pragma unroll
    for (int b = 0; b < 8; b++) { ar[b] = 0.f; az[b] = 0.f; an[b] = 0.f; }

    for (int k4 = lane; k4 < H3 / 4; k4 += 64) {        // 9 iters
        float4 w4r = wr[k4], w4z = wz[k4], w4n = wn[k4];
#pragma unroll
        for (int b = 0; b < 8; b++) {
            float4 x4 = ((const float4*)(x + b * H3))[k4];
            ar[b] += w4r.x * x4.x + w4r.y * x4.y + w4r.z * x4.z + w4r.w * x4.w;
            az[b] += w4z.x * x4.x + w4z.y * x4.y + w4z.z * x4.z + w4z.w * x4.w;
            an[b] += w4n.x * x4.x + w4n.y * x4.y + w4n.z * x4.z + w4n.w * x4.w;
        }
    }
#pragma unroll
    for (int b = 0; b < 8; b++) {
        float vr = ar[b], vz = az[b], vn = an[b];
        for (int off = 32; off; off >>= 1) {
            vr += __shfl_down(vr, off, 64);
            vz += __shfl_down(vz, off, 64);
            vn += __shfl_down(vn, off, 64);
        }
        ar[b] = vr; az[b] = vz; an[b] = vn;
    }
    if (lane == 0) {
        float bi_r = b_ih[j], bi_z = b_ih[HDIM + j], bi_n = b_ih[2 * HDIM + j];
#pragma unroll
        for (int b = 0; b < 8; b++) {
            float gir = ar[b] + bi_r;
            float giz = az[b] + bi_z;
            float gin = an[b] + bi_n;
            float ghr = ghb[b * H3 + j];
            float ghz = ghb[b * H3 + HDIM + j];
            float ghn = ghb[b * H3 + 2 * HDIM + j];
            float r = 1.f / (1.f + expf(-(gir + ghr)));
            float z = 1.f / (1.f + expf(-(giz + ghz)));
            float n = tanhf(gin + r * ghn);
            hout[b * HDIM + j] = (1.f - z) * n + z * hin[b * HDIM + j];
        }
    }
}

// ---------------------------------------------------------------------------
// Per-row routing for bigmv: which matrix / bias / destination row r maps to.
// ---------------------------------------------------------------------------
struct RowT { const float* w; const float* bias; float* dst; int stride; int neg; };

__device__ __forceinline__ RowT row_info(
    int r,
    const float* copy_w, const float* copy_b,
    const float* out_w,  const float* out_b,
    const float* attn_w, const float* attn_b,
    const float* w_hh,   const float* b_hh,
    float* th2, float* gen, float* thb, float* ghb)
{
    RowT t;
    if (r < HDIM) {
        t.w = copy_w + (size_t)r * HDIM; t.bias = copy_b + r;
        t.dst = th2 + r; t.stride = HDIM; t.neg = 0;
    } else if (r < HDIM + VDIM) {
        int v = r - HDIM;
        t.w = out_w + (size_t)v * HDIM; t.bias = out_b + v;
        t.dst = gen + v; t.stride = VDIM; t.neg = (v == 0);
    } else if (r < 2 * HDIM + VDIM) {
        int rr = r - HDIM - VDIM;
        t.w = attn_w + (size_t)rr * HDIM; t.bias = attn_b + rr;
        t.dst = thb + rr; t.stride = HDIM; t.neg = 0;
    } else {
        int rr = r - 2 * HDIM - VDIM;
        t.w = w_hh + (size_t)rr * HDIM; t.bias = b_hh + rr;
        t.dst = ghb + rr; t.stride = H3; t.neg = 0;
    }
    return t;
}

// ---------------------------------------------------------------------------
// bigmv: stream copy_w | out_w | attn_w | w_hh against LDS-staged h'.
// 1074 blocks x 512; 8 waves x 4 rows each (32 rows/block).
// ---------------------------------------------------------------------------
__global__ __launch_bounds__(512) void bigmv_kernel(
    const float* __restrict__ copy_w, const float* __restrict__ copy_b,
    const float* __restrict__ out_w,  const float* __restrict__ out_b,
    const float* __restrict__ attn_w, const float* __restrict__ attn_b,
    const float* __restrict__ w_hh,   const float* __restrict__ b_hh,
    const float* __restrict__ hp, float* __restrict__ th2,
    float* __restrict__ gen, float* __restrict__ thb,
    float* __restrict__ ghb)
{
    __shared__ float xs[BDIM * HDIM];
    for (int i = threadIdx.x; i < BDIM * HDIM; i += 512)
        xs[i] = hp[i];
    __syncthreads();

    int wid = threadIdx.x >> 6, lane = threadIdx.x & 63;
    int r0 = blockIdx.x * 32 + wid * 4;
    if (r0 >= NROWS) return;

    int rc0 = r0, rc1 = min(r0 + 1, NROWS - 1);
    int rc2 = min(r0 + 2, NROWS - 1), rc3 = min(r0 + 3, NROWS - 1);
    RowT t0 = row_info(rc0, copy_w, copy_b, out_w, out_b, attn_w, attn_b,
                       w_hh, b_hh, th2, gen, thb, ghb);
    RowT t1 = row_info(rc1, copy_w, copy_b, out_w, out_b, attn_w, attn_b,
                       w_hh, b_hh, th2, gen, thb, ghb);
    RowT t2 = row_info(rc2, copy_w, copy_b, out_w, out_b, attn_w, attn_b,
                       w_hh, b_hh, th2, gen, thb, ghb);
    RowT t3 = row_info(rc3, copy_w, copy_b, out_w, out_b, attn_w, attn_b,
                       w_hh, b_hh, th2, gen, thb, ghb);

    float a0[8], a1[8], a2[8], a3[8];
#pragma unroll
    for (int b = 0; b < 8; b++) { a0[b] = 0.f; a1[b] = 0.f; a2[b] = 0.f; a3[b] = 0.f; }

    const float4* w0 = (const float4*)t0.w;
    const float4* w1 = (const float4*)t1.w;
    const float4* w2 = (const float4*)t2.w;
    const float4* w3 = (const float4*)t3.w;

    for (int k4 = lane; k4 < HDIM / 4; k4 += 64) {      // 3 iterations
        float4 q0 = w0[k4], q1 = w1[k4], q2 = w2[k4], q3 = w3[k4];
#pragma unroll
        for (int b = 0; b < 8; b++) {
            float4 x4 = ((const float4*)(xs + b * HDIM))[k4];
            a0[b] += q0.x * x4.x + q0.y * x4.y + q0.z * x4.z + q0.w * x4.w;
            a1[b] += q1.x * x4.x + q1.y * x4.y + q1.z * x4.z + q1.w * x4.w;
            a2[b] += q2.x * x4.x + q2.y * x4.y + q2.z * x4.z + q2.w * x4.w;
            a3[b] += q3.x * x4.x + q3.y * x4.y + q3.z * x4.z + q3.w * x4.w;
        }
    }
#pragma unroll
    for (int b = 0; b < 8; b++) {
        float v0 = a0[b], v1 = a1[b], v2 = a2[b], v3 = a3[b];
        for (int off = 32; off; off >>= 1) {
            v0 += __shfl_down(v0, off, 64);
            v1 += __shfl_down(v1, off, 64);
            v2 += __shfl_down(v2, off, 64);
            v3 += __shfl_down(v3, off, 64);
        }
        a0[b] = v0; a1[b] = v1; a2[b] = v2; a3[b] = v3;
    }
    if (lane == 0) {
        float bb0 = t0.bias[0], bb1 = t1.bias[0], bb2 = t2.bias[0], bb3 = t3.bias[0];
#pragma unroll
        for (int b = 0; b < 8; b++) {
            t0.dst[(size_t)b * t0.stride] = t0.neg ? NEGV : a0[b] + bb0;
            if (r0 + 1 < NROWS) t1.dst[(size_t)b * t1.stride] = t1.neg ? NEGV : a1[b] + bb1;
            if (r0 + 2 < NROWS) t2.dst[(size_t)b * t2.stride] = t2.neg ? NEGV : a2[b] + bb2;
            if (r0 + 3 < NROWS) t3.dst[(size_t)b * t3.stride] = t3.neg ? NEGV : a3[b] + bb3;
        }
    }
}

// ---------------------------------------------------------------------------
// combo: block (b,sub): enc s-slice -> scores(t+1) (vs th) AND css(t) (vs
// th2) in one pass; attn softmax partial + partial context; gen-stats slice.
// 64 blocks x 512.
// ---------------------------------------------------------------------------
__global__ __launch_bounds__(512) void combo_kernel(
    const float* __restrict__ enc, const float* __restrict__ thb,
    const float* __restrict__ th2, float* __restrict__ css,
    float* __restrict__ atC, float* __restrict__ atM, float* __restrict__ atZ,
    const float* __restrict__ gen, float* __restrict__ gM,
    float* __restrict__ gZ, int do_cg)
{
    __shared__ float sth[HDIM];
    __shared__ float sth2[HDIM];
    __shared__ float swe[SSLICE];
    __shared__ float red[8];
    int blk = blockIdx.x, b = blk >> 3, sub = blk & 7;
    int tid = threadIdx.x, wid = tid >> 6, lane = tid & 63;
    int slo = sub * SSLICE;

    for (int i = tid; i < HDIM; i += 512) {
        sth[i]  = thb[b * HDIM + i];
        sth2[i] = th2[b * HDIM + i];
    }
    __syncthreads();

    // dual dots per enc row
    for (int j = 0; j < 8; j++) {
        int sl = wid * 8 + j, s = slo + sl;
        const float4* er = (const float4*)(enc + ((size_t)b * SDIM + s) * HDIM);
        float a1 = 0.f, a2 = 0.f;
#pragma unroll
        for (int i = 0; i < 3; i++) {
            float4 e = er[lane + i * 64];
            float4 t1 = ((const float4*)sth)[lane + i * 64];
            float4 t2 = ((const float4*)sth2)[lane + i * 64];
            a1 += e.x * t1.x + e.y * t1.y + e.z * t1.z + e.w * t1.w;
            a2 += e.x * t2.x + e.y * t2.y + e.z * t2.z + e.w * t2.w;
        }
        for (int off = 32; off; off >>= 1) {
            a1 += __shfl_down(a1, off, 64);
            a2 += __shfl_down(a2, off, 64);
        }
        if (lane == 0) {
            swe[sl] = a1;
            if (do_cg) css[b * SDIM + s] = a2;
        }
    }
    __syncthreads();

    // softmax partial over the 64 scores
    if (tid < 64) {
        float v = swe[tid];
        float m = v;
        for (int off = 32; off; off >>= 1) m = fmaxf(m, __shfl_xor(m, off, 64));
        float e = expf(v - m);
        float z = e;
        for (int off = 32; off; off >>= 1) z += __shfl_xor(z, off, 64);
        swe[tid] = e;
        if (tid == 0) { atM[b * 8 + sub] = m; atZ[b * 8 + sub] = z; }
    }
    __syncthreads();

    // partial context (coalesced cols)
    for (int col = tid; col < HDIM; col += 512) {
        float acc = 0.f;
        const float* eb = enc + ((size_t)b * SDIM + slo) * HDIM + col;
#pragma unroll 8
        for (int s2 = 0; s2 < SSLICE; s2++) acc += swe[s2] * eb[s2 * HDIM];
        atC[((size_t)b * 8 + sub) * HDIM + col] = acc;
    }

    if (!do_cg) return;

    // gen stats over v-slice
    int vlo = sub * VSLICE, vhi = min(VDIM, vlo + VSLICE);
    const float* grow = gen + (size_t)b * VDIM;
    float m = -INFINITY;
    for (int v = vlo + tid; v < vhi; v += 512) m = fmaxf(m, grow[v]);
    for (int off = 32; off; off >>= 1) m = fmaxf(m, __shfl_xor(m, off, 64));
    if (lane == 0) red[wid] = m;
    __syncthreads();
    float M = red[0];
#pragma unroll
    for (int w = 1; w < 8; w++) M = fmaxf(M, red[w]);
    float z = 0.f;
    for (int v = vlo + tid; v < vhi; v += 512) z += expf(grow[v] - M);
    for (int off = 32; off; off >>= 1) z += __shfl_xor(z, off, 64);
    __syncthreads();
    if (lane == 0) red[wid] = z;
    __syncthreads();
    if (tid == 0) {
        float Z = 0.f;
#pragma unroll
        for (int w = 0; w < 8; w++) Z += red[w];
        gM[b * 8 + sub] = M;
        gZ[b * 8 + sub] = Z;
    }
}

// ---------------------------------------------------------------------------
// tailc: copy agg + M/Z combine + log-probs + argmax partials. 64 x 1024.
// ---------------------------------------------------------------------------
__global__ __launch_bounds__(1024) void tailc_kernel(
    const float* __restrict__ gen, const float* __restrict__ css,
    const int* __restrict__ inputs, const float* __restrict__ genM,
    const float* __restrict__ genZ, float* __restrict__ dout,
    float* __restrict__ argV, int* __restrict__ argI, int t)
{
    __shared__ int   toks[SDIM];
    __shared__ float csss[SDIM];
    __shared__ float aggv[SDIM];
    __shared__ unsigned char ffl[SDIM];
    __shared__ float redf[1024];
    __shared__ int   redi[1024];
    int blk = blockIdx.x, b = blk >> 3, sub = blk & 7;
    int tid = threadIdx.x;

    if (tid < SDIM) {
        toks[tid] = inputs[b * SDIM + tid];
        csss[tid] = css[b * SDIM + tid];
    }
    __syncthreads();

    if (tid < SDIM) {
        int tok = toks[tid]; int isf = 0; float agg = -INFINITY;
        if (tok != 0) {
            isf = 1;
            for (int s2 = 0; s2 < tid; s2++)
                if (toks[s2] == tok) { isf = 0; break; }
            if (isf) {
                float ss = 0.f;
                for (int s2 = tid; s2 < SDIM; s2++)
                    if (toks[s2] == tok) ss += csss[s2];
                agg = ss;
            }
        }
        ffl[tid] = (unsigned char)isf;
        aggv[tid] = agg;
    }
    __syncthreads();

    redf[tid] = (tid < SDIM && ffl[tid]) ? aggv[tid] : -INFINITY;
    __syncthreads();
    for (int off = 512; off; off >>= 1) {
        if (tid < off) redf[tid] = fmaxf(redf[tid], redf[tid + off]);
        __syncthreads();
    }
    float m9 = redf[0]; __syncthreads();
    redf[tid] = (tid < SDIM && ffl[tid] && m9 > -INFINITY)
                    ? expf(aggv[tid] - m9) : 0.f;
    __syncthreads();
    for (int off = 512; off; off >>= 1) {
        if (tid < off) redf[tid] += redf[tid + off];
        __syncthreads();
    }
    float z9 = redf[0]; __syncthreads();

    float M = genM[b * 8 + 0];
#pragma unroll
    for (int i = 1; i < 8; i++) M = fmaxf(M, genM[b * 8 + i]);
    if (m9 > -INFINITY) M = fmaxf(M, m9);
    float Z = 0.f;
#pragma unroll
    for (int i = 0; i < 8; i++) Z += genZ[b * 8 + i] * expf(genM[b * 8 + i] - M);
    if (m9 > -INFINITY) Z += z9 * expf(m9 - M);
    float invZ = 1.f / Z;

    const float* grow = gen + (size_t)b * VDIM;
    float* orow = dout + ((size_t)b * TLEN + t + 1) * VT;
    int vlo = sub * VSLICE, vhi = min(VDIM, vlo + VSLICE);
    float best = -INFINITY; int bidx = 2147483647;
    for (int v = vlo + tid; v < vhi; v += 1024) {
        float pg = expf(grow[v] - M) * invZ;
        float lp = logf(pg + 1e-10f);
        orow[v] = lp;
        if (lp > best) { best = lp; bidx = v; }
    }
    if (sub == 0 && tid < SDIM) orow[VDIM + tid] = logf(1e-10f);
    __syncthreads();

    if (tid < SDIM && ffl[tid]) {
        int tok = toks[tid];
        if (tok >= vlo && tok < vhi) {
            float pc = expf(aggv[tid] - M) * invZ;
            float pg = expf(grow[tok] - M) * invZ;
            float lp = logf(pg + pc + 1e-10f);
            orow[tok] = lp;
            if (lp > best || (lp == best && tok < bidx)) { best = lp; bidx = tok; }
        }
    }
    redf[tid] = best; redi[tid] = bidx; __syncthreads();
    for (int off = 512; off; off >>= 1) {
        if (tid < off) {
            float v2 = redf[tid + off]; int i2 = redi[tid + off];
            if (v2 > redf[tid] || (v2 == redf[tid] && i2 < redi[tid])) {
                redf[tid] = v2; redi[tid] = i2;
            }
        }
        __syncthreads();
    }
    if (tid == 0) { argV[b * 8 + sub] = redf[0]; argI[b * 8 + sub] = redi[0]; }
}

// ---------------------------------------------------------------------------
// mix: blocks 0..7 = tail_d (argmax combine, samp, selread+embed);
//      blocks 8..15 = attn_fin (ctx combine -> x[:,0:H)). 16 x 1024.
// ---------------------------------------------------------------------------
__global__ __launch_bounds__(1024) void mix_kernel(
    const float* __restrict__ enc, const float* __restrict__ css,
    const int* __restrict__ inputs, const float* __restrict__ argV,
    const int* __restrict__ argI, const float* __restrict__ emb,
    float* __restrict__ dout, float* __restrict__ x,
    const float* __restrict__ atC, const float* __restrict__ atM,
    const float* __restrict__ atZ, int t, int do_tail)
{
    __shared__ int   toks[SDIM];
    __shared__ float csss[SDIM];
    __shared__ float redf[1024];
    __shared__ int   mlist[SDIM];
    __shared__ float mscore[SDIM];
    __shared__ int   wcnt[16], woff[16];
    __shared__ int   mtot;
    int bid = blockIdx.x, tid = threadIdx.x;

    if (bid >= BDIM) {
        // attn_fin
        int b = bid - BDIM;
        if (tid < HDIM) {
            float m[8], z[8];
#pragma unroll
            for (int i = 0; i < 8; i++) { m[i] = atM[b * 8 + i]; z[i] = atZ[b * 8 + i]; }
            float M = m[0];
#pragma unroll
            for (int i = 1; i < 8; i++) M = fmaxf(M, m[i]);
            float Z = 0.f;
#pragma unroll
            for (int i = 0; i < 8; i++) Z += z[i] * expf(m[i] - M);
            float acc = 0.f;
#pragma unroll
            for (int i = 0; i < 8; i++)
                acc += atC[((size_t)b * 8 + i) * HDIM + tid] * expf(m[i] - M);
            x[b * H3 + tid] = acc / Z;
        }
        return;
    }
    if (!do_tail) return;

    int b = bid;
    float best = argV[b * 8 + 0]; int samp = argI[b * 8 + 0];
#pragma unroll
    for (int i = 1; i < 8; i++) {
        float v = argV[b * 8 + i];
        if (v > best) { best = v; samp = argI[b * 8 + i]; }
    }
    if (tid == 0) dout[OFF2 + (size_t)b * TLEN + t + 1] = (float)samp;

    if (tid < SDIM) {
        toks[tid] = inputs[b * SDIM + tid];
        csss[tid] = css[b * SDIM + tid];
    }
    __syncthreads();

    int flag = (tid < SDIM) ? (toks[tid] == samp) : 0;
    redf[tid] = flag ? fabsf(csss[tid]) : 0.f;
    __syncthreads();
    for (int off = 512; off; off >>= 1) {
        if (tid < off) redf[tid] += redf[tid + off];
        __syncthreads();
    }
    float den = fmaxf(redf[0], 1e-12f);
    __syncthreads();

    unsigned long long mk = __ballot(flag);
    int wv = tid >> 6, ln = tid & 63;
    if (ln == 0) wcnt[wv] = __popcll(mk);
    __syncthreads();
    if (tid == 0) {
        int o = 0;
        for (int w = 0; w < 16; w++) { woff[w] = o; o += wcnt[w]; }
        mtot = o;
    }
    __syncthreads();
    if (flag) {
        int pos = woff[wv] + __popcll(mk & ((1ULL << ln) - 1ULL));
        mlist[pos] = tid;
        mscore[pos] = csss[tid] / den;
    }
    __syncthreads();
    int mc = mtot;

    if (tid < HDIM) {
        float sel = 0.f;
        for (int mI = 0; mI < mc; mI++)
            sel += mscore[mI] * enc[((size_t)b * SDIM + mlist[mI]) * HDIM + tid];
        x[b * H3 + HDIM + tid] = sel;
        int ic = (samp > VDIM) ? 3 : samp;
        if (ic >= VDIM) ic = VDIM - 1;
        x[b * H3 + 2 * HDIM + tid] = emb[(size_t)ic * HDIM + tid];
    }
}

// ---------------------------------------------------------------------------
extern "C" void kernel_launch(void* const* d_in, const int* in_sizes, int n_in,
                              void* d_out, int out_size, void* d_ws, size_t ws_size,
                              hipStream_t stream)
{
    const float* enc    = (const float*)d_in[0];
    const int*   inputs = (const int*)d_in[1];
    const int*   cls    = (const int*)d_in[2];
    const float* emb    = (const float*)d_in[4];
    const float* attn_w = (const float*)d_in[5];
    const float* attn_b = (const float*)d_in[6];
    const float* copy_w = (const float*)d_in[7];
    const float* copy_b = (const float*)d_in[8];
    const float* w_ih   = (const float*)d_in[9];
    const float* w_hh   = (const float*)d_in[10];
    const float* b_ih   = (const float*)d_in[11];
    const float* b_hh   = (const float*)d_in[12];
    const float* out_w  = (const float*)d_in[13];
    const float* out_b  = (const float*)d_in[14];
    float* dout = (float*)d_out;

    float* ws   = (float*)d_ws;
    float* hA   = ws;                          // B*H
    float* hB   = hA  + BDIM * HDIM;           // B*H
    float* x    = hB  + BDIM * HDIM;           // B*H3
    float* thb  = x   + BDIM * H3;             // B*H
    float* ghb  = thb + BDIM * HDIM;           // B*H3
    float* th2  = ghb + BDIM * H3;             // B*H
    float* gen  = th2 + BDIM * HDIM;           // B*V
    float* css  = gen + (size_t)BDIM * VDIM;   // B*S
    float* atC  = css + BDIM * SDIM;           // B*8*H
    float* atM  = atC + BDIM * 8 * HDIM;       // 64
    float* atZ  = atM + 64;
    float* gM   = atZ + 64;
    float* gZ   = gM  + 64;
    float* argV = gZ  + 64;
    int*   argI = (int*)(argV + 64);

    boot_kernel<<<512, 256, 0, stream>>>(dout, cls, hA, x, emb, thb, ghb,
                                         attn_b, b_hh);
    // attention partials for t=0 (scores from th0; no css/gen yet)
    combo_kernel<<<64, 512, 0, stream>>>(enc, thb, th2, css, atC, atM, atZ,
                                         gen, gM, gZ, 0);
    // ctx combine -> x0 (tail off)
    mix_kernel<<<16, 1024, 0, stream>>>(enc, css, inputs, argV, argI, emb,
                                        dout, x, atC, atM, atZ, 0, 0);

    for (int t = 0; t < TLEN - 1; t++) {
        const float* hin  = (t & 1) ? hB : hA;
        float*       hout = (t & 1) ? hA : hB;
        grufull_kernel<<<96, 512, 0, stream>>>(w_ih, b_ih, x, ghb, hin, hout);
        bigmv_kernel<<<(NROWS + 31) / 32, 512, 0, stream>>>(
            copy_w, copy_b, out_w, out_b, attn_w, attn_b, w_hh, b_hh,
            hout, th2, gen, thb, ghb);
        combo_kernel<<<64, 512, 0, stream>>>(enc, thb, th2, css, atC, atM, atZ,
                                             gen, gM, gZ, 1);
        tailc_kernel<<<64, 1024, 0, stream>>>(gen, css, inputs, gM, gZ,
                                              dout, argV, argI, t);
        mix_kernel<<<16, 1024, 0, stream>>>(enc, css, inputs, argV, argI, emb,
                                            dout, x, atC, atM, atZ, t, 1);
    }
}

// Round 8
// 3342.433 us; speedup vs baseline: 3.1330x; 1.1252x over previous
//
#include <hip/hip_runtime.h>
#include <hip/hip_bf16.h>
#include <math.h>

#define HDIM 768
#define SDIM 512
#define VDIM 30522
#define BDIM 8
#define TLEN 32
#define H3   2304
#define VT   31034          // V + S
#define NEGV -1.0e6f
#define OFF2 ((size_t)BDIM * TLEN * VT)   // 7944704
#define SSLICE 64                          // s-slice per combo block
#define VSLICE 3816                        // ceil(V/8)
#define NROWS (HDIM + VDIM + HDIM + H3)    // 34362 bigmv rows

// ---------------------------------------------------------------------------
// Boot: dout init; h0 = 0; th0 = attn_b; gh0 = b_hh; x sel/emb init.
// ---------------------------------------------------------------------------
__global__ __launch_bounds__(256) void boot_kernel(
    float* __restrict__ dout, const int* __restrict__ cls,
    float* __restrict__ hA, float* __restrict__ x,
    const float* __restrict__ emb, float* __restrict__ thb,
    float* __restrict__ ghb, const float* __restrict__ attn_b,
    const float* __restrict__ b_hh)
{
    int gidx = blockIdx.x * 256 + threadIdx.x;
    int stride = gridDim.x * 256;
    float clsv = (float)cls[0];
    for (int i = gidx; i < BDIM * VT; i += stride) {
        int b = i / VT, v = i % VT;
        dout[(size_t)b * TLEN * VT + v] = (v == 0) ? clsv : 0.f;
    }
    if (gidx < BDIM) dout[OFF2 + (size_t)gidx * TLEN] = 1.0f;
    for (int i = gidx; i < BDIM * HDIM; i += stride) {
        int b = i / HDIM, j = i % HDIM;
        hA[i] = 0.f;
        x[b * H3 + HDIM + j] = 0.f;
        x[b * H3 + 2 * HDIM + j] = emb[HDIM + j];
        thb[i] = attn_b[j];
    }
    for (int i = gidx; i < BDIM * H3; i += stride)
        ghb[i] = b_hh[i % H3];
}

// ---------------------------------------------------------------------------
// grufull: all 3 gate rows of gi for output j computed in ONE k-loop
// (x4 loaded once, used by 3 gates), then GRU combine. 96 blocks x 512.
// ---------------------------------------------------------------------------
__global__ __launch_bounds__(512) void grufull_kernel(
    const float* __restrict__ w_ih, const float* __restrict__ b_ih,
    const float* __restrict__ x, const float* __restrict__ ghb,
    const float* __restrict__ hin, float* __restrict__ hout)
{
    int wid = threadIdx.x >> 6, lane = threadIdx.x & 63;
    int j = blockIdx.x * 8 + wid;
    if (j >= HDIM) return;

    const float4* wr = (const float4*)(w_ih + (size_t)j * H3);
    const float4* wz = (const float4*)(w_ih + (size_t)(HDIM + j) * H3);
    const float4* wn = (const float4*)(w_ih + (size_t)(2 * HDIM + j) * H3);

    float ar[8], az[8], an[8];
#pragma unroll
    for (int b = 0; b < 8; b++) { ar[b] = 0.f; az[b] = 0.f; an[b] = 0.f; }

    for (int k4 = lane; k4 < H3 / 4; k4 += 64) {        // 9 iters
        float4 w4r = wr[k4], w4z = wz[k4], w4n = wn[k4];
#pragma unroll
        for (int b = 0; b < 8; b++) {
            float4 x4 = ((const float4*)(x + b * H3))[k4];
            ar[b] += w4r.x * x4.x + w4r.y * x4.y + w4r.z * x4.z + w4r.w * x4.w;
            az[b] += w4z.x * x4.x + w4z.y * x4.y + w4z.z * x4.z + w4z.w * x4.w;
            an[b] += w4n.x * x4.x + w4n.y * x4.y + w4n.z * x4.z + w4n.w * x4.w;
        }
    }
#pragma unroll
    for (int b = 0; b < 8; b++) {
        float vr = ar[b], vz = az[b], vn = an[b];
        for (int off = 32; off; off >>= 1) {
            vr += __shfl_down(vr, off, 64);
            vz += __shfl_down(vz, off, 64);
            vn += __shfl_down(vn, off, 64);
        }
        ar[b] = vr; az[b] = vz; an[b] = vn;
    }
    if (lane == 0) {
        float bi_r = b_ih[j], bi_z = b_ih[HDIM + j], bi_n = b_ih[2 * HDIM + j];
#pragma unroll
        for (int b = 0; b < 8; b++) {
            float gir = ar[b] + bi_r;
            float giz = az[b] + bi_z;
            float gin = an[b] + bi_n;
            float ghr = ghb[b * H3 + j];
            float ghz = ghb[b * H3 + HDIM + j];
            float ghn = ghb[b * H3 + 2 * HDIM + j];
            float r = 1.f / (1.f + expf(-(gir + ghr)));
            float z = 1.f / (1.f + expf(-(giz + ghz)));
            float n = tanhf(gin + r * ghn);
            hout[b * HDIM + j] = (1.f - z) * n + z * hin[b * HDIM + j];
        }
    }
}

// ---------------------------------------------------------------------------
// Per-row routing for bigmv: which matrix / bias / destination row r maps to.
// ---------------------------------------------------------------------------
struct RowT { const float* w; const float* bias; float* dst; int stride; int neg; };

__device__ __forceinline__ RowT row_info(
    int r,
    const float* copy_w, const float* copy_b,
    const float* out_w,  const float* out_b,
    const float* attn_w, const float* attn_b,
    const float* w_hh,   const float* b_hh,
    float* th2, float* gen, float* thb, float* ghb)
{
    RowT t;
    if (r < HDIM) {
        t.w = copy_w + (size_t)r * HDIM; t.bias = copy_b + r;
        t.dst = th2 + r; t.stride = HDIM; t.neg = 0;
    } else if (r < HDIM + VDIM) {
        int v = r - HDIM;
        t.w = out_w + (size_t)v * HDIM; t.bias = out_b + v;
        t.dst = gen + v; t.stride = VDIM; t.neg = (v == 0);
    } else if (r < 2 * HDIM + VDIM) {
        int rr = r - HDIM - VDIM;
        t.w = attn_w + (size_t)rr * HDIM; t.bias = attn_b + rr;
        t.dst = thb + rr; t.stride = HDIM; t.neg = 0;
    } else {
        int rr = r - 2 * HDIM - VDIM;
        t.w = w_hh + (size_t)rr * HDIM; t.bias = b_hh + rr;
        t.dst = ghb + rr; t.stride = H3; t.neg = 0;
    }
    return t;
}

// ---------------------------------------------------------------------------
// bigmv: stream copy_w | out_w | attn_w | w_hh against LDS-staged h'.
// 2148 blocks x 256 threads; 4 waves x 4 rows each (16 rows/block).
// Small blocks keep 6 blocks/CU resident (LDS cap) with 8+ rounds of
// turnover; 12 independent weight loads in flight per wave.
// ---------------------------------------------------------------------------
__global__ __launch_bounds__(256) void bigmv_kernel(
    const float* __restrict__ copy_w, const float* __restrict__ copy_b,
    const float* __restrict__ out_w,  const float* __restrict__ out_b,
    const float* __restrict__ attn_w, const float* __restrict__ attn_b,
    const float* __restrict__ w_hh,   const float* __restrict__ b_hh,
    const float* __restrict__ hp, float* __restrict__ th2,
    float* __restrict__ gen, float* __restrict__ thb,
    float* __restrict__ ghb)
{
    __shared__ float xs[BDIM * HDIM];
    {
        const float4* s4 = (const float4*)hp;
        float4* d4 = (float4*)xs;
#pragma unroll
        for (int i = 0; i < 6; i++)
            d4[threadIdx.x + i * 256] = s4[threadIdx.x + i * 256];
    }
    __syncthreads();

    int wid = threadIdx.x >> 6, lane = threadIdx.x & 63;
    int r0 = blockIdx.x * 16 + wid * 4;
    if (r0 >= NROWS) return;

    int rc1 = min(r0 + 1, NROWS - 1);
    int rc2 = min(r0 + 2, NROWS - 1), rc3 = min(r0 + 3, NROWS - 1);
    RowT t0 = row_info(r0,  copy_w, copy_b, out_w, out_b, attn_w, attn_b,
                       w_hh, b_hh, th2, gen, thb, ghb);
    RowT t1 = row_info(rc1, copy_w, copy_b, out_w, out_b, attn_w, attn_b,
                       w_hh, b_hh, th2, gen, thb, ghb);
    RowT t2 = row_info(rc2, copy_w, copy_b, out_w, out_b, attn_w, attn_b,
                       w_hh, b_hh, th2, gen, thb, ghb);
    RowT t3 = row_info(rc3, copy_w, copy_b, out_w, out_b, attn_w, attn_b,
                       w_hh, b_hh, th2, gen, thb, ghb);

    float a0[8], a1[8], a2[8], a3[8];
#pragma unroll
    for (int b = 0; b < 8; b++) { a0[b] = 0.f; a1[b] = 0.f; a2[b] = 0.f; a3[b] = 0.f; }

    const float4* w0 = (const float4*)t0.w;
    const float4* w1 = (const float4*)t1.w;
    const float4* w2 = (const float4*)t2.w;
    const float4* w3 = (const float4*)t3.w;

#pragma unroll
    for (int i = 0; i < 3; i++) {                       // K = 768, 3 x 64 lanes
        int k4 = lane + i * 64;
        float4 q0 = w0[k4], q1 = w1[k4], q2 = w2[k4], q3 = w3[k4];
#pragma unroll
        for (int b = 0; b < 8; b++) {
            float4 x4 = ((const float4*)(xs + b * HDIM))[k4];
            a0[b] += q0.x * x4.x + q0.y * x4.y + q0.z * x4.z + q0.w * x4.w;
            a1[b] += q1.x * x4.x + q1.y * x4.y + q1.z * x4.z + q1.w * x4.w;
            a2[b] += q2.x * x4.x + q2.y * x4.y + q2.z * x4.z + q2.w * x4.w;
            a3[b] += q3.x * x4.x + q3.y * x4.y + q3.z * x4.z + q3.w * x4.w;
        }
    }
#pragma unroll
    for (int b = 0; b < 8; b++) {
        float v0 = a0[b], v1 = a1[b], v2 = a2[b], v3 = a3[b];
        for (int off = 32; off; off >>= 1) {
            v0 += __shfl_down(v0, off, 64);
            v1 += __shfl_down(v1, off, 64);
            v2 += __shfl_down(v2, off, 64);
            v3 += __shfl_down(v3, off, 64);
        }
        a0[b] = v0; a1[b] = v1; a2[b] = v2; a3[b] = v3;
    }
    if (lane == 0) {
        float bb0 = t0.bias[0], bb1 = t1.bias[0], bb2 = t2.bias[0], bb3 = t3.bias[0];
#pragma unroll
        for (int b = 0; b < 8; b++) {
            t0.dst[(size_t)b * t0.stride] = t0.neg ? NEGV : a0[b] + bb0;
            if (r0 + 1 < NROWS) t1.dst[(size_t)b * t1.stride] = t1.neg ? NEGV : a1[b] + bb1;
            if (r0 + 2 < NROWS) t2.dst[(size_t)b * t2.stride] = t2.neg ? NEGV : a2[b] + bb2;
            if (r0 + 3 < NROWS) t3.dst[(size_t)b * t3.stride] = t3.neg ? NEGV : a3[b] + bb3;
        }
    }
}

// ---------------------------------------------------------------------------
// combo: block (b,sub): enc s-slice -> scores(t+1) (vs th) AND css(t) (vs
// th2) in one pass; attn softmax partial + partial context; gen-stats slice.
// 64 blocks x 512.
// ---------------------------------------------------------------------------
__global__ __launch_bounds__(512) void combo_kernel(
    const float* __restrict__ enc, const float* __restrict__ thb,
    const float* __restrict__ th2, float* __restrict__ css,
    float* __restrict__ atC, float* __restrict__ atM, float* __restrict__ atZ,
    const float* __restrict__ gen, float* __restrict__ gM,
    float* __restrict__ gZ, int do_cg)
{
    __shared__ float sth[HDIM];
    __shared__ float sth2[HDIM];
    __shared__ float swe[SSLICE];
    __shared__ float red[8];
    int blk = blockIdx.x, b = blk >> 3, sub = blk & 7;
    int tid = threadIdx.x, wid = tid >> 6, lane = tid & 63;
    int slo = sub * SSLICE;

    for (int i = tid; i < HDIM; i += 512) {
        sth[i]  = thb[b * HDIM + i];
        sth2[i] = th2[b * HDIM + i];
    }
    __syncthreads();

    // dual dots per enc row
    for (int j = 0; j < 8; j++) {
        int sl = wid * 8 + j, s = slo + sl;
        const float4* er = (const float4*)(enc + ((size_t)b * SDIM + s) * HDIM);
        float a1 = 0.f, a2 = 0.f;
#pragma unroll
        for (int i = 0; i < 3; i++) {
            float4 e = er[lane + i * 64];
            float4 t1 = ((const float4*)sth)[lane + i * 64];
            float4 t2 = ((const float4*)sth2)[lane + i * 64];
            a1 += e.x * t1.x + e.y * t1.y + e.z * t1.z + e.w * t1.w;
            a2 += e.x * t2.x + e.y * t2.y + e.z * t2.z + e.w * t2.w;
        }
        for (int off = 32; off; off >>= 1) {
            a1 += __shfl_down(a1, off, 64);
            a2 += __shfl_down(a2, off, 64);
        }
        if (lane == 0) {
            swe[sl] = a1;
            if (do_cg) css[b * SDIM + s] = a2;
        }
    }
    __syncthreads();

    // softmax partial over the 64 scores
    if (tid < 64) {
        float v = swe[tid];
        float m = v;
        for (int off = 32; off; off >>= 1) m = fmaxf(m, __shfl_xor(m, off, 64));
        float e = expf(v - m);
        float z = e;
        for (int off = 32; off; off >>= 1) z += __shfl_xor(z, off, 64);
        swe[tid] = e;
        if (tid == 0) { atM[b * 8 + sub] = m; atZ[b * 8 + sub] = z; }
    }
    __syncthreads();

    // partial context (coalesced cols)
    for (int col = tid; col < HDIM; col += 512) {
        float acc = 0.f;
        const float* eb = enc + ((size_t)b * SDIM + slo) * HDIM + col;
#pragma unroll 8
        for (int s2 = 0; s2 < SSLICE; s2++) acc += swe[s2] * eb[s2 * HDIM];
        atC[((size_t)b * 8 + sub) * HDIM + col] = acc;
    }

    if (!do_cg) return;

    // gen stats over v-slice
    int vlo = sub * VSLICE, vhi = min(VDIM, vlo + VSLICE);
    const float* grow = gen + (size_t)b * VDIM;
    float m = -INFINITY;
    for (int v = vlo + tid; v < vhi; v += 512) m = fmaxf(m, grow[v]);
    for (int off = 32; off; off >>= 1) m = fmaxf(m, __shfl_xor(m, off, 64));
    if (lane == 0) red[wid] = m;
    __syncthreads();
    float M = red[0];
#pragma unroll
    for (int w = 1; w < 8; w++) M = fmaxf(M, red[w]);
    float z = 0.f;
    for (int v = vlo + tid; v < vhi; v += 512) z += expf(grow[v] - M);
    for (int off = 32; off; off >>= 1) z += __shfl_xor(z, off, 64);
    __syncthreads();
    if (lane == 0) red[wid] = z;
    __syncthreads();
    if (tid == 0) {
        float Z = 0.f;
#pragma unroll
        for (int w = 0; w < 8; w++) Z += red[w];
        gM[b * 8 + sub] = M;
        gZ[b * 8 + sub] = Z;
    }
}

// ---------------------------------------------------------------------------
// tailc: copy agg + M/Z combine + log-probs + argmax partials. 64 x 1024.
// ---------------------------------------------------------------------------
__global__ __launch_bounds__(1024) void tailc_kernel(
    const float* __restrict__ gen, const float* __restrict__ css,
    const int* __restrict__ inputs, const float* __restrict__ genM,
    const float* __restrict__ genZ, float* __restrict__ dout,
    float* __restrict__ argV, int* __restrict__ argI, int t)
{
    __shared__ int   toks[SDIM];
    __shared__ float csss[SDIM];
    __shared__ float aggv[SDIM];
    __shared__ unsigned char ffl[SDIM];
    __shared__ float redf[1024];
    __shared__ int   redi[1024];
    int blk = blockIdx.x, b = blk >> 3, sub = blk & 7;
    int tid = threadIdx.x;

    if (tid < SDIM) {
        toks[tid] = inputs[b * SDIM + tid];
        csss[tid] = css[b * SDIM + tid];
    }
    __syncthreads();

    if (tid < SDIM) {
        int tok = toks[tid]; int isf = 0; float agg = -INFINITY;
        if (tok != 0) {
            isf = 1;
            for (int s2 = 0; s2 < tid; s2++)
                if (toks[s2] == tok) { isf = 0; break; }
            if (isf) {
                float ss = 0.f;
                for (int s2 = tid; s2 < SDIM; s2++)
                    if (toks[s2] == tok) ss += csss[s2];
                agg = ss;
            }
        }
        ffl[tid] = (unsigned char)isf;
        aggv[tid] = agg;
    }
    __syncthreads();

    redf[tid] = (tid < SDIM && ffl[tid]) ? aggv[tid] : -INFINITY;
    __syncthreads();
    for (int off = 512; off; off >>= 1) {
        if (tid < off) redf[tid] = fmaxf(redf[tid], redf[tid + off]);
        __syncthreads();
    }
    float m9 = redf[0]; __syncthreads();
    redf[tid] = (tid < SDIM && ffl[tid] && m9 > -INFINITY)
                    ? expf(aggv[tid] - m9) : 0.f;
    __syncthreads();
    for (int off = 512; off; off >>= 1) {
        if (tid < off) redf[tid] += redf[tid + off];
        __syncthreads();
    }
    float z9 = redf[0]; __syncthreads();

    float M = genM[b * 8 + 0];
#pragma unroll
    for (int i = 1; i < 8; i++) M = fmaxf(M, genM[b * 8 + i]);
    if (m9 > -INFINITY) M = fmaxf(M, m9);
    float Z = 0.f;
#pragma unroll
    for (int i = 0; i < 8; i++) Z += genZ[b * 8 + i] * expf(genM[b * 8 + i] - M);
    if (m9 > -INFINITY) Z += z9 * expf(m9 - M);
    float invZ = 1.f / Z;

    const float* grow = gen + (size_t)b * VDIM;
    float* orow = dout + ((size_t)b * TLEN + t + 1) * VT;
    int vlo = sub * VSLICE, vhi = min(VDIM, vlo + VSLICE);
    float best = -INFINITY; int bidx = 2147483647;
    for (int v = vlo + tid; v < vhi; v += 1024) {
        float pg = expf(grow[v] - M) * invZ;
        float lp = logf(pg + 1e-10f);
        orow[v] = lp;
        if (lp > best) { best = lp; bidx = v; }
    }
    if (sub == 0 && tid < SDIM) orow[VDIM + tid] = logf(1e-10f);
    __syncthreads();

    if (tid < SDIM && ffl[tid]) {
        int tok = toks[tid];
        if (tok >= vlo && tok < vhi) {
            float pc = expf(aggv[tid] - M) * invZ;
            float pg = expf(grow[tok] - M) * invZ;
            float lp = logf(pg + pc + 1e-10f);
            orow[tok] = lp;
            if (lp > best || (lp == best && tok < bidx)) { best = lp; bidx = tok; }
        }
    }
    redf[tid] = best; redi[tid] = bidx; __syncthreads();
    for (int off = 512; off; off >>= 1) {
        if (tid < off) {
            float v2 = redf[tid + off]; int i2 = redi[tid + off];
            if (v2 > redf[tid] || (v2 == redf[tid] && i2 < redi[tid])) {
                redf[tid] = v2; redi[tid] = i2;
            }
        }
        __syncthreads();
    }
    if (tid == 0) { argV[b * 8 + sub] = redf[0]; argI[b * 8 + sub] = redi[0]; }
}

// ---------------------------------------------------------------------------
// mix: blocks 0..7 = tail_d (argmax combine, samp, selread+embed);
//      blocks 8..15 = attn_fin (ctx combine -> x[:,0:H)). 16 x 1024.
// ---------------------------------------------------------------------------
__global__ __launch_bounds__(1024) void mix_kernel(
    const float* __restrict__ enc, const float* __restrict__ css,
    const int* __restrict__ inputs, const float* __restrict__ argV,
    const int* __restrict__ argI, const float* __restrict__ emb,
    float* __restrict__ dout, float* __restrict__ x,
    const float* __restrict__ atC, const float* __restrict__ atM,
    const float* __restrict__ atZ, int t, int do_tail)
{
    __shared__ int   toks[SDIM];
    __shared__ float csss[SDIM];
    __shared__ float redf[1024];
    __shared__ int   mlist[SDIM];
    __shared__ float mscore[SDIM];
    __shared__ int   wcnt[16], woff[16];
    __shared__ int   mtot;
    int bid = blockIdx.x, tid = threadIdx.x;

    if (bid >= BDIM) {
        // attn_fin
        int b = bid - BDIM;
        if (tid < HDIM) {
            float m[8], z[8];
#pragma unroll
            for (int i = 0; i < 8; i++) { m[i] = atM[b * 8 + i]; z[i] = atZ[b * 8 + i]; }
            float M = m[0];
#pragma unroll
            for (int i = 1; i < 8; i++) M = fmaxf(M, m[i]);
            float Z = 0.f;
#pragma unroll
            for (int i = 0; i < 8; i++) Z += z[i] * expf(m[i] - M);
            float acc = 0.f;
#pragma unroll
            for (int i = 0; i < 8; i++)
                acc += atC[((size_t)b * 8 + i) * HDIM + tid] * expf(m[i] - M);
            x[b * H3 + tid] = acc / Z;
        }
        return;
    }
    if (!do_tail) return;

    int b = bid;
    float best = argV[b * 8 + 0]; int samp = argI[b * 8 + 0];
#pragma unroll
    for (int i = 1; i < 8; i++) {
        float v = argV[b * 8 + i];
        if (v > best) { best = v; samp = argI[b * 8 + i]; }
    }
    if (tid == 0) dout[OFF2 + (size_t)b * TLEN + t + 1] = (float)samp;

    if (tid < SDIM) {
        toks[tid] = inputs[b * SDIM + tid];
        csss[tid] = css[b * SDIM + tid];
    }
    __syncthreads();

    int flag = (tid < SDIM) ? (toks[tid] == samp) : 0;
    redf[tid] = flag ? fabsf(csss[tid]) : 0.f;
    __syncthreads();
    for (int off = 512; off; off >>= 1) {
        if (tid < off) redf[tid] += redf[tid + off];
        __syncthreads();
    }
    float den = fmaxf(redf[0], 1e-12f);
    __syncthreads();

    unsigned long long mk = __ballot(flag);
    int wv = tid >> 6, ln = tid & 63;
    if (ln == 0) wcnt[wv] = __popcll(mk);
    __syncthreads();
    if (tid == 0) {
        int o = 0;
        for (int w = 0; w < 16; w++) { woff[w] = o; o += wcnt[w]; }
        mtot = o;
    }
    __syncthreads();
    if (flag) {
        int pos = woff[wv] + __popcll(mk & ((1ULL << ln) - 1ULL));
        mlist[pos] = tid;
        mscore[pos] = csss[tid] / den;
    }
    __syncthreads();
    int mc = mtot;

    if (tid < HDIM) {
        float sel = 0.f;
        for (int mI = 0; mI < mc; mI++)
            sel += mscore[mI] * enc[((size_t)b * SDIM + mlist[mI]) * HDIM + tid];
        x[b * H3 + HDIM + tid] = sel;
        int ic = (samp > VDIM) ? 3 : samp;
        if (ic >= VDIM) ic = VDIM - 1;
        x[b * H3 + 2 * HDIM + tid] = emb[(size_t)ic * HDIM + tid];
    }
}

// ---------------------------------------------------------------------------
extern "C" void kernel_launch(void* const* d_in, const int* in_sizes, int n_in,
                              void* d_out, int out_size, void* d_ws, size_t ws_size,
                              hipStream_t stream)
{
    const float* enc    = (const float*)d_in[0];
    const int*   inputs = (const int*)d_in[1];
    const int*   cls    = (const int*)d_in[2];
    const float* emb    = (const float*)d_in[4];
    const float* attn_w = (const float*)d_in[5];
    const float* attn_b = (const float*)d_in[6];
    const float* copy_w = (const float*)d_in[7];
    const float* copy_b = (const float*)d_in[8];
    const float* w_ih   = (const float*)d_in[9];
    const float* w_hh   = (const float*)d_in[10];
    const float* b_ih   = (const float*)d_in[11];
    const float* b_hh   = (const float*)d_in[12];
    const float* out_w  = (const float*)d_in[13];
    const float* out_b  = (const float*)d_in[14];
    float* dout = (float*)d_out;

    float* ws   = (float*)d_ws;
    float* hA   = ws;                          // B*H
    float* hB   = hA  + BDIM * HDIM;           // B*H
    float* x    = hB  + BDIM * HDIM;           // B*H3
    float* thb  = x   + BDIM * H3;             // B*H
    float* ghb  = thb + BDIM * HDIM;           // B*H3
    float* th2  = ghb + BDIM * H3;             // B*H
    float* gen  = th2 + BDIM * HDIM;           // B*V
    float* css  = gen + (size_t)BDIM * VDIM;   // B*S
    float* atC  = css + BDIM * SDIM;           // B*8*H
    float* atM  = atC + BDIM * 8 * HDIM;       // 64
    float* atZ  = atM + 64;
    float* gM   = atZ + 64;
    float* gZ   = gM  + 64;
    float* argV = gZ  + 64;
    int*   argI = (int*)(argV + 64);

    boot_kernel<<<512, 256, 0, stream>>>(dout, cls, hA, x, emb, thb, ghb,
                                         attn_b, b_hh);
    // attention partials for t=0 (scores from th0; no css/gen yet)
    combo_kernel<<<64, 512, 0, stream>>>(enc, thb, th2, css, atC, atM, atZ,
                                         gen, gM, gZ, 0);
    // ctx combine -> x0 (tail off)
    mix_kernel<<<16, 1024, 0, stream>>>(enc, css, inputs, argV, argI, emb,
                                        dout, x, atC, atM, atZ, 0, 0);

    for (int t = 0; t < TLEN - 1; t++) {
        const float* hin  = (t & 1) ? hB : hA;
        float*       hout = (t & 1) ? hA : hB;
        grufull_kernel<<<96, 512, 0, stream>>>(w_ih, b_ih, x, ghb, hin, hout);
        bigmv_kernel<<<(NROWS + 15) / 16, 256, 0, stream>>>(
            copy_w, copy_b, out_w, out_b, attn_w, attn_b, w_hh, b_hh,
            hout, th2, gen, thb, ghb);
        combo_kernel<<<64, 512, 0, stream>>>(enc, thb, th2, css, atC, atM, atZ,
                                             gen, gM, gZ, 1);
        tailc_kernel<<<64, 1024, 0, stream>>>(gen, css, inputs, gM, gZ,
                                              dout, argV, argI, t);
        mix_kernel<<<16, 1024, 0, stream>>>(enc, css, inputs, argV, argI, emb,
                                            dout, x, atC, atM, atZ, t, 1);
    }
}

// Round 9
// 3298.049 us; speedup vs baseline: 3.1751x; 1.0135x over previous
//
#include <hip/hip_runtime.h>
#include <hip/hip_bf16.h>
#include <math.h>

#define HDIM 768
#define SDIM 512
#define VDIM 30522
#define BDIM 8
#define TLEN 32
#define H3   2304
#define VT   31034          // V + S
#define NEGV -1.0e6f
#define OFF2 ((size_t)BDIM * TLEN * VT)   // 7944704
#define NSUB 32                            // s/v subslices for combo
#define SSL  16                            // SDIM / NSUB
#define VSL  954                           // ceil(VDIM/32)
#define VSLICE 3816                        // ceil(V/8) for tailc output slices
#define NROWS (HDIM + VDIM + HDIM + H3)    // 34362 bigmv rows

// ---------------------------------------------------------------------------
// Boot: dout init; h0 = 0; th0 = attn_b; gh0 = b_hh; x sel/emb init.
// ---------------------------------------------------------------------------
__global__ __launch_bounds__(256) void boot_kernel(
    float* __restrict__ dout, const int* __restrict__ cls,
    float* __restrict__ hA, float* __restrict__ x,
    const float* __restrict__ emb, float* __restrict__ thb,
    float* __restrict__ ghb, const float* __restrict__ attn_b,
    const float* __restrict__ b_hh)
{
    int gidx = blockIdx.x * 256 + threadIdx.x;
    int stride = gridDim.x * 256;
    float clsv = (float)cls[0];
    for (int i = gidx; i < BDIM * VT; i += stride) {
        int b = i / VT, v = i % VT;
        dout[(size_t)b * TLEN * VT + v] = (v == 0) ? clsv : 0.f;
    }
    if (gidx < BDIM) dout[OFF2 + (size_t)gidx * TLEN] = 1.0f;
    for (int i = gidx; i < BDIM * HDIM; i += stride) {
        int b = i / HDIM, j = i % HDIM;
        hA[i] = 0.f;
        x[b * H3 + HDIM + j] = 0.f;
        x[b * H3 + 2 * HDIM + j] = emb[HDIM + j];
        thb[i] = attn_b[j];
    }
    for (int i = gidx; i < BDIM * H3; i += stride)
        ghb[i] = b_hh[i % H3];
}

// ---------------------------------------------------------------------------
// grufull: one wave per output j (768 blocks x 64 threads) -> all CUs busy.
// All 3 gate rows in one k-loop (x4 loaded once per gate triple), then GRU.
// ---------------------------------------------------------------------------
__global__ __launch_bounds__(64) void grufull_kernel(
    const float* __restrict__ w_ih, const float* __restrict__ b_ih,
    const float* __restrict__ x, const float* __restrict__ ghb,
    const float* __restrict__ hin, float* __restrict__ hout)
{
    int lane = threadIdx.x;
    int j = blockIdx.x;

    const float4* wr = (const float4*)(w_ih + (size_t)j * H3);
    const float4* wz = (const float4*)(w_ih + (size_t)(HDIM + j) * H3);
    const float4* wn = (const float4*)(w_ih + (size_t)(2 * HDIM + j) * H3);

    float ar[8], az[8], an[8];
#pragma unroll
    for (int b = 0; b < 8; b++) { ar[b] = 0.f; az[b] = 0.f; an[b] = 0.f; }

    for (int k4 = lane; k4 < H3 / 4; k4 += 64) {        // 9 iters
        float4 w4r = wr[k4], w4z = wz[k4], w4n = wn[k4];
#pragma unroll
        for (int b = 0; b < 8; b++) {
            float4 x4 = ((const float4*)(x + b * H3))[k4];
            ar[b] += w4r.x * x4.x + w4r.y * x4.y + w4r.z * x4.z + w4r.w * x4.w;
            az[b] += w4z.x * x4.x + w4z.y * x4.y + w4z.z * x4.z + w4z.w * x4.w;
            an[b] += w4n.x * x4.x + w4n.y * x4.y + w4n.z * x4.z + w4n.w * x4.w;
        }
    }
#pragma unroll
    for (int b = 0; b < 8; b++) {
        float vr = ar[b], vz = az[b], vn = an[b];
        for (int off = 32; off; off >>= 1) {
            vr += __shfl_down(vr, off, 64);
            vz += __shfl_down(vz, off, 64);
            vn += __shfl_down(vn, off, 64);
        }
        ar[b] = vr; az[b] = vz; an[b] = vn;
    }
    if (lane == 0) {
        float bi_r = b_ih[j], bi_z = b_ih[HDIM + j], bi_n = b_ih[2 * HDIM + j];
#pragma unroll
        for (int b = 0; b < 8; b++) {
            float gir = ar[b] + bi_r;
            float giz = az[b] + bi_z;
            float gin = an[b] + bi_n;
            float ghr = ghb[b * H3 + j];
            float ghz = ghb[b * H3 + HDIM + j];
            float ghn = ghb[b * H3 + 2 * HDIM + j];
            float r = 1.f / (1.f + expf(-(gir + ghr)));
            float z = 1.f / (1.f + expf(-(giz + ghz)));
            float n = tanhf(gin + r * ghn);
            hout[b * HDIM + j] = (1.f - z) * n + z * hin[b * HDIM + j];
        }
    }
}

// ---------------------------------------------------------------------------
// Per-row routing for bigmv.
// ---------------------------------------------------------------------------
struct RowT { const float* w; const float* bias; float* dst; int stride; int neg; };

__device__ __forceinline__ RowT row_info(
    int r,
    const float* copy_w, const float* copy_b,
    const float* out_w,  const float* out_b,
    const float* attn_w, const float* attn_b,
    const float* w_hh,   const float* b_hh,
    float* th2, float* gen, float* thb, float* ghb)
{
    RowT t;
    if (r < HDIM) {
        t.w = copy_w + (size_t)r * HDIM; t.bias = copy_b + r;
        t.dst = th2 + r; t.stride = HDIM; t.neg = 0;
    } else if (r < HDIM + VDIM) {
        int v = r - HDIM;
        t.w = out_w + (size_t)v * HDIM; t.bias = out_b + v;
        t.dst = gen + v; t.stride = VDIM; t.neg = (v == 0);
    } else if (r < 2 * HDIM + VDIM) {
        int rr = r - HDIM - VDIM;
        t.w = attn_w + (size_t)rr * HDIM; t.bias = attn_b + rr;
        t.dst = thb + rr; t.stride = HDIM; t.neg = 0;
    } else {
        int rr = r - 2 * HDIM - VDIM;
        t.w = w_hh + (size_t)rr * HDIM; t.bias = b_hh + rr;
        t.dst = ghb + rr; t.stride = H3; t.neg = 0;
    }
    return t;
}

// ---------------------------------------------------------------------------
// bigmv: stream copy_w | out_w | attn_w | w_hh against x read DIRECTLY from
// global (hp = 24 KB -> L1-resident on every CU; identical addresses across
// waves). No LDS, no barrier -> occupancy VGPR-bound, free turnover.
// 2148 blocks x 256 threads; 4 waves x 4 rows each.
// ---------------------------------------------------------------------------
__global__ __launch_bounds__(256) void bigmv_kernel(
    const float* __restrict__ copy_w, const float* __restrict__ copy_b,
    const float* __restrict__ out_w,  const float* __restrict__ out_b,
    const float* __restrict__ attn_w, const float* __restrict__ attn_b,
    const float* __restrict__ w_hh,   const float* __restrict__ b_hh,
    const float* __restrict__ hp, float* __restrict__ th2,
    float* __restrict__ gen, float* __restrict__ thb,
    float* __restrict__ ghb)
{
    int wid = threadIdx.x >> 6, lane = threadIdx.x & 63;
    int r0 = blockIdx.x * 16 + wid * 4;
    if (r0 >= NROWS) return;

    int rc1 = min(r0 + 1, NROWS - 1);
    int rc2 = min(r0 + 2, NROWS - 1), rc3 = min(r0 + 3, NROWS - 1);
    RowT t0 = row_info(r0,  copy_w, copy_b, out_w, out_b, attn_w, attn_b,
                       w_hh, b_hh, th2, gen, thb, ghb);
    RowT t1 = row_info(rc1, copy_w, copy_b, out_w, out_b, attn_w, attn_b,
                       w_hh, b_hh, th2, gen, thb, ghb);
    RowT t2 = row_info(rc2, copy_w, copy_b, out_w, out_b, attn_w, attn_b,
                       w_hh, b_hh, th2, gen, thb, ghb);
    RowT t3 = row_info(rc3, copy_w, copy_b, out_w, out_b, attn_w, attn_b,
                       w_hh, b_hh, th2, gen, thb, ghb);

    float a0[8], a1[8], a2[8], a3[8];
#pragma unroll
    for (int b = 0; b < 8; b++) { a0[b] = 0.f; a1[b] = 0.f; a2[b] = 0.f; a3[b] = 0.f; }

    const float4* w0 = (const float4*)t0.w;
    const float4* w1 = (const float4*)t1.w;
    const float4* w2 = (const float4*)t2.w;
    const float4* w3 = (const float4*)t3.w;
    const float4* xb = (const float4*)hp;          // [b * 192 + k4]

#pragma unroll
    for (int i = 0; i < 3; i++) {                  // K = 768, 3 x 64 lanes
        int k4 = lane + i * 64;
        float4 q0 = w0[k4], q1 = w1[k4], q2 = w2[k4], q3 = w3[k4];
#pragma unroll
        for (int b = 0; b < 8; b++) {
            float4 x4 = xb[b * 192 + k4];
            a0[b] += q0.x * x4.x + q0.y * x4.y + q0.z * x4.z + q0.w * x4.w;
            a1[b] += q1.x * x4.x + q1.y * x4.y + q1.z * x4.z + q1.w * x4.w;
            a2[b] += q2.x * x4.x + q2.y * x4.y + q2.z * x4.z + q2.w * x4.w;
            a3[b] += q3.x * x4.x + q3.y * x4.y + q3.z * x4.z + q3.w * x4.w;
        }
    }
#pragma unroll
    for (int b = 0; b < 8; b++) {
        float v0 = a0[b], v1 = a1[b], v2 = a2[b], v3 = a3[b];
        for (int off = 32; off; off >>= 1) {
            v0 += __shfl_down(v0, off, 64);
            v1 += __shfl_down(v1, off, 64);
            v2 += __shfl_down(v2, off, 64);
            v3 += __shfl_down(v3, off, 64);
        }
        a0[b] = v0; a1[b] = v1; a2[b] = v2; a3[b] = v3;
    }
    if (lane == 0) {
        float bb0 = t0.bias[0], bb1 = t1.bias[0], bb2 = t2.bias[0], bb3 = t3.bias[0];
#pragma unroll
        for (int b = 0; b < 8; b++) {
            t0.dst[(size_t)b * t0.stride] = t0.neg ? NEGV : a0[b] + bb0;
            if (r0 + 1 < NROWS) t1.dst[(size_t)b * t1.stride] = t1.neg ? NEGV : a1[b] + bb1;
            if (r0 + 2 < NROWS) t2.dst[(size_t)b * t2.stride] = t2.neg ? NEGV : a2[b] + bb2;
            if (r0 + 3 < NROWS) t3.dst[(size_t)b * t3.stride] = t3.neg ? NEGV : a3[b] + bb3;
        }
    }
}

// ---------------------------------------------------------------------------
// combo: block (b,sub): sub in [0,32), s-slice of 16. Dual dots (th for
// attention t+1 scores, th2 for css), softmax partial, partial context,
// gen-stats slice. 256 blocks x 512.
// ---------------------------------------------------------------------------
__global__ __launch_bounds__(512) void combo_kernel(
    const float* __restrict__ enc, const float* __restrict__ thb,
    const float* __restrict__ th2, float* __restrict__ css,
    float* __restrict__ atC, float* __restrict__ atM, float* __restrict__ atZ,
    const float* __restrict__ gen, float* __restrict__ gM,
    float* __restrict__ gZ, int do_cg)
{
    __shared__ float sth[HDIM];
    __shared__ float sth2[HDIM];
    __shared__ float swe[SSL];
    __shared__ float red[8];
    int blk = blockIdx.x, b = blk >> 5, sub = blk & 31;
    int tid = threadIdx.x, wid = tid >> 6, lane = tid & 63;
    int slo = sub * SSL;

    for (int i = tid; i < HDIM; i += 512) {
        sth[i]  = thb[b * HDIM + i];
        sth2[i] = th2[b * HDIM + i];
    }
    __syncthreads();

    // dual dots: 2 s per wave
    for (int j = 0; j < 2; j++) {
        int sl = wid * 2 + j, s = slo + sl;
        const float4* er = (const float4*)(enc + ((size_t)b * SDIM + s) * HDIM);
        float a1 = 0.f, a2 = 0.f;
#pragma unroll
        for (int i = 0; i < 3; i++) {
            float4 e = er[lane + i * 64];
            float4 t1 = ((const float4*)sth)[lane + i * 64];
            float4 t2 = ((const float4*)sth2)[lane + i * 64];
            a1 += e.x * t1.x + e.y * t1.y + e.z * t1.z + e.w * t1.w;
            a2 += e.x * t2.x + e.y * t2.y + e.z * t2.z + e.w * t2.w;
        }
        for (int off = 32; off; off >>= 1) {
            a1 += __shfl_down(a1, off, 64);
            a2 += __shfl_down(a2, off, 64);
        }
        if (lane == 0) {
            swe[sl] = a1;
            if (do_cg) css[b * SDIM + s] = a2;
        }
    }
    __syncthreads();

    // softmax partial over the 16 scores
    if (tid == 0) {
        float m = swe[0];
        for (int i = 1; i < SSL; i++) m = fmaxf(m, swe[i]);
        float z = 0.f;
        for (int i = 0; i < SSL; i++) { float e = expf(swe[i] - m); swe[i] = e; z += e; }
        atM[b * NSUB + sub] = m;
        atZ[b * NSUB + sub] = z;
    }
    __syncthreads();

    // partial context (coalesced cols)
    for (int col = tid; col < HDIM; col += 512) {
        float acc = 0.f;
        const float* eb = enc + ((size_t)b * SDIM + slo) * HDIM + col;
#pragma unroll
        for (int s2 = 0; s2 < SSL; s2++) acc += swe[s2] * eb[s2 * HDIM];
        atC[((size_t)b * NSUB + sub) * HDIM + col] = acc;
    }

    if (!do_cg) return;

    // gen stats over v-slice
    int vlo = sub * VSL, vhi = min(VDIM, vlo + VSL);
    const float* grow = gen + (size_t)b * VDIM;
    float m = -INFINITY;
    for (int v = vlo + tid; v < vhi; v += 512) m = fmaxf(m, grow[v]);
    for (int off = 32; off; off >>= 1) m = fmaxf(m, __shfl_xor(m, off, 64));
    if (lane == 0) red[wid] = m;
    __syncthreads();
    float M = red[0];
#pragma unroll
    for (int w = 1; w < 8; w++) M = fmaxf(M, red[w]);
    float z = 0.f;
    for (int v = vlo + tid; v < vhi; v += 512) z += expf(grow[v] - M);
    for (int off = 32; off; off >>= 1) z += __shfl_xor(z, off, 64);
    __syncthreads();
    if (lane == 0) red[wid] = z;
    __syncthreads();
    if (tid == 0) {
        float Z = 0.f;
#pragma unroll
        for (int w = 0; w < 8; w++) Z += red[w];
        gM[b * NSUB + sub] = M;
        gZ[b * NSUB + sub] = Z;
    }
}

// ---------------------------------------------------------------------------
// tailc: copy agg + M/Z combine (32 gen partials, fixed order) + log-probs
// + argmax partials. 64 x 1024 (8 output v-slices per batch).
// ---------------------------------------------------------------------------
__global__ __launch_bounds__(1024) void tailc_kernel(
    const float* __restrict__ gen, const float* __restrict__ css,
    const int* __restrict__ inputs, const float* __restrict__ genM,
    const float* __restrict__ genZ, float* __restrict__ dout,
    float* __restrict__ argV, int* __restrict__ argI, int t)
{
    __shared__ int   toks[SDIM];
    __shared__ float csss[SDIM];
    __shared__ float aggv[SDIM];
    __shared__ unsigned char ffl[SDIM];
    __shared__ float redf[1024];
    __shared__ int   redi[1024];
    int blk = blockIdx.x, b = blk >> 3, sub = blk & 7;
    int tid = threadIdx.x;

    if (tid < SDIM) {
        toks[tid] = inputs[b * SDIM + tid];
        csss[tid] = css[b * SDIM + tid];
    }
    __syncthreads();

    if (tid < SDIM) {
        int tok = toks[tid]; int isf = 0; float agg = -INFINITY;
        if (tok != 0) {
            isf = 1;
            for (int s2 = 0; s2 < tid; s2++)
                if (toks[s2] == tok) { isf = 0; break; }
            if (isf) {
                float ss = 0.f;
                for (int s2 = tid; s2 < SDIM; s2++)
                    if (toks[s2] == tok) ss += csss[s2];
                agg = ss;
            }
        }
        ffl[tid] = (unsigned char)isf;
        aggv[tid] = agg;
    }
    __syncthreads();

    redf[tid] = (tid < SDIM && ffl[tid]) ? aggv[tid] : -INFINITY;
    __syncthreads();
    for (int off = 512; off; off >>= 1) {
        if (tid < off) redf[tid] = fmaxf(redf[tid], redf[tid + off]);
        __syncthreads();
    }
    float m9 = redf[0]; __syncthreads();
    redf[tid] = (tid < SDIM && ffl[tid] && m9 > -INFINITY)
                    ? expf(aggv[tid] - m9) : 0.f;
    __syncthreads();
    for (int off = 512; off; off >>= 1) {
        if (tid < off) redf[tid] += redf[tid + off];
        __syncthreads();
    }
    float z9 = redf[0]; __syncthreads();

    float M = genM[b * NSUB + 0];
#pragma unroll
    for (int i = 1; i < NSUB; i++) M = fmaxf(M, genM[b * NSUB + i]);
    if (m9 > -INFINITY) M = fmaxf(M, m9);
    float Z = 0.f;
#pragma unroll
    for (int i = 0; i < NSUB; i++)
        Z += genZ[b * NSUB + i] * expf(genM[b * NSUB + i] - M);
    if (m9 > -INFINITY) Z += z9 * expf(m9 - M);
    float invZ = 1.f / Z;

    const float* grow = gen + (size_t)b * VDIM;
    float* orow = dout + ((size_t)b * TLEN + t + 1) * VT;
    int vlo = sub * VSLICE, vhi = min(VDIM, vlo + VSLICE);
    float best = -INFINITY; int bidx = 2147483647;
    for (int v = vlo + tid; v < vhi; v += 1024) {
        float pg = expf(grow[v] - M) * invZ;
        float lp = logf(pg + 1e-10f);
        orow[v] = lp;
        if (lp > best) { best = lp; bidx = v; }
    }
    if (sub == 0 && tid < SDIM) orow[VDIM + tid] = logf(1e-10f);
    __syncthreads();

    if (tid < SDIM && ffl[tid]) {
        int tok = toks[tid];
        if (tok >= vlo && tok < vhi) {
            float pc = expf(aggv[tid] - M) * invZ;
            float pg = expf(grow[tok] - M) * invZ;
            float lp = logf(pg + pc + 1e-10f);
            orow[tok] = lp;
            if (lp > best || (lp == best && tok < bidx)) { best = lp; bidx = tok; }
        }
    }
    redf[tid] = best; redi[tid] = bidx; __syncthreads();
    for (int off = 512; off; off >>= 1) {
        if (tid < off) {
            float v2 = redf[tid + off]; int i2 = redi[tid + off];
            if (v2 > redf[tid] || (v2 == redf[tid] && i2 < redi[tid])) {
                redf[tid] = v2; redi[tid] = i2;
            }
        }
        __syncthreads();
    }
    if (tid == 0) { argV[b * 8 + sub] = redf[0]; argI[b * 8 + sub] = redi[0]; }
}

// ---------------------------------------------------------------------------
// mix: blocks 0..7 = tail_d (argmax combine, samp, selread+embed);
//      blocks 8..15 = attn_fin (32-partial flash combine -> x[:,0:H)).
// ---------------------------------------------------------------------------
__global__ __launch_bounds__(1024) void mix_kernel(
    const float* __restrict__ enc, const float* __restrict__ css,
    const int* __restrict__ inputs, const float* __restrict__ argV,
    const int* __restrict__ argI, const float* __restrict__ emb,
    float* __restrict__ dout, float* __restrict__ x,
    const float* __restrict__ atC, const float* __restrict__ atM,
    const float* __restrict__ atZ, int t, int do_tail)
{
    __shared__ int   toks[SDIM];
    __shared__ float csss[SDIM];
    __shared__ float redf[1024];
    __shared__ int   mlist[SDIM];
    __shared__ float mscore[SDIM];
    __shared__ int   wcnt[16], woff[16];
    __shared__ int   mtot;
    int bid = blockIdx.x, tid = threadIdx.x;

    if (bid >= BDIM) {
        // attn_fin: combine 32 partials (fixed ascending order)
        int b = bid - BDIM;
        if (tid < HDIM) {
            float M = atM[b * NSUB];
#pragma unroll
            for (int i = 1; i < NSUB; i++) M = fmaxf(M, atM[b * NSUB + i]);
            float Z = 0.f, acc = 0.f;
#pragma unroll
            for (int i = 0; i < NSUB; i++) {
                float sc = expf(atM[b * NSUB + i] - M);
                Z += atZ[b * NSUB + i] * sc;
                acc += atC[((size_t)b * NSUB + i) * HDIM + tid] * sc;
            }
            x[b * H3 + tid] = acc / Z;
        }
        return;
    }
    if (!do_tail) return;

    int b = bid;
    float best = argV[b * 8 + 0]; int samp = argI[b * 8 + 0];
#pragma unroll
    for (int i = 1; i < 8; i++) {
        float v = argV[b * 8 + i];
        if (v > best) { best = v; samp = argI[b * 8 + i]; }
    }
    if (tid == 0) dout[OFF2 + (size_t)b * TLEN + t + 1] = (float)samp;

    if (tid < SDIM) {
        toks[tid] = inputs[b * SDIM + tid];
        csss[tid] = css[b * SDIM + tid];
    }
    __syncthreads();

    int flag = (tid < SDIM) ? (toks[tid] == samp) : 0;
    redf[tid] = flag ? fabsf(csss[tid]) : 0.f;
    __syncthreads();
    for (int off = 512; off; off >>= 1) {
        if (tid < off) redf[tid] += redf[tid + off];
        __syncthreads();
    }
    float den = fmaxf(redf[0], 1e-12f);
    __syncthreads();

    unsigned long long mk = __ballot(flag);
    int wv = tid >> 6, ln = tid & 63;
    if (ln == 0) wcnt[wv] = __popcll(mk);
    __syncthreads();
    if (tid == 0) {
        int o = 0;
        for (int w = 0; w < 16; w++) { woff[w] = o; o += wcnt[w]; }
        mtot = o;
    }
    __syncthreads();
    if (flag) {
        int pos = woff[wv] + __popcll(mk & ((1ULL << ln) - 1ULL));
        mlist[pos] = tid;
        mscore[pos] = csss[tid] / den;
    }
    __syncthreads();
    int mc = mtot;

    if (tid < HDIM) {
        float sel = 0.f;
        for (int mI = 0; mI < mc; mI++)
            sel += mscore[mI] * enc[((size_t)b * SDIM + mlist[mI]) * HDIM + tid];
        x[b * H3 + HDIM + tid] = sel;
        int ic = (samp > VDIM) ? 3 : samp;
        if (ic >= VDIM) ic = VDIM - 1;
        x[b * H3 + 2 * HDIM + tid] = emb[(size_t)ic * HDIM + tid];
    }
}

// ---------------------------------------------------------------------------
extern "C" void kernel_launch(void* const* d_in, const int* in_sizes, int n_in,
                              void* d_out, int out_size, void* d_ws, size_t ws_size,
                              hipStream_t stream)
{
    const float* enc    = (const float*)d_in[0];
    const int*   inputs = (const int*)d_in[1];
    const int*   cls    = (const int*)d_in[2];
    const float* emb    = (const float*)d_in[4];
    const float* attn_w = (const float*)d_in[5];
    const float* attn_b = (const float*)d_in[6];
    const float* copy_w = (const float*)d_in[7];
    const float* copy_b = (const float*)d_in[8];
    const float* w_ih   = (const float*)d_in[9];
    const float* w_hh   = (const float*)d_in[10];
    const float* b_ih   = (const float*)d_in[11];
    const float* b_hh   = (const float*)d_in[12];
    const float* out_w  = (const float*)d_in[13];
    const float* out_b  = (const float*)d_in[14];
    float* dout = (float*)d_out;

    float* ws   = (float*)d_ws;
    float* hA   = ws;                          // B*H
    float* hB   = hA  + BDIM * HDIM;           // B*H
    float* x    = hB  + BDIM * HDIM;           // B*H3
    float* thb  = x   + BDIM * H3;             // B*H
    float* ghb  = thb + BDIM * HDIM;           // B*H3
    float* th2  = ghb + BDIM * H3;             // B*H
    float* gen  = th2 + BDIM * HDIM;           // B*V
    float* css  = gen + (size_t)BDIM * VDIM;   // B*S
    float* atC  = css + BDIM * SDIM;           // B*32*H
    float* atM  = atC + (size_t)BDIM * NSUB * HDIM;   // 256
    float* atZ  = atM + BDIM * NSUB;
    float* gM   = atZ + BDIM * NSUB;
    float* gZ   = gM  + BDIM * NSUB;
    float* argV = gZ  + BDIM * NSUB;
    int*   argI = (int*)(argV + 64);

    boot_kernel<<<512, 256, 0, stream>>>(dout, cls, hA, x, emb, thb, ghb,
                                         attn_b, b_hh);
    // attention partials for t=0 (scores from th0; no css/gen yet)
    combo_kernel<<<256, 512, 0, stream>>>(enc, thb, th2, css, atC, atM, atZ,
                                          gen, gM, gZ, 0);
    // ctx combine -> x0 (tail off)
    mix_kernel<<<16, 1024, 0, stream>>>(enc, css, inputs, argV, argI, emb,
                                        dout, x, atC, atM, atZ, 0, 0);

    for (int t = 0; t < TLEN - 1; t++) {
        const float* hin  = (t & 1) ? hB : hA;
        float*       hout = (t & 1) ? hA : hB;
        grufull_kernel<<<HDIM, 64, 0, stream>>>(w_ih, b_ih, x, ghb, hin, hout);
        bigmv_kernel<<<(NROWS + 15) / 16, 256, 0, stream>>>(
            copy_w, copy_b, out_w, out_b, attn_w, attn_b, w_hh, b_hh,
            hout, th2, gen, thb, ghb);
        combo_kernel<<<256, 512, 0, stream>>>(enc, thb, th2, css, atC, atM, atZ,
                                              gen, gM, gZ, 1);
        tailc_kernel<<<64, 1024, 0, stream>>>(gen, css, inputs, gM, gZ,
                                              dout, argV, argI, t);
        mix_kernel<<<16, 1024, 0, stream>>>(enc, css, inputs, argV, argI, emb,
                                            dout, x, atC, atM, atZ, t, 1);
    }
}